// Round 1
// baseline (330.517 us; speedup 1.0000x reference)
//
#include <hip/hip_runtime.h>
#include <hip/hip_cooperative_groups.h>

namespace cg = cooperative_groups;

// Bottom-up HTMM on a complete 4-ary tree, depth 7 (t_size=21845).
// children(u)=4u+1..4u+4, pos(u)=(u-1)&3; only labels t[u*7] are data.
// prior cancels everywhere (only numbeta = prior*beta_il is used).
//
// R10: ONE cooperative kernel (256 blocks x 512, grid.sync x3).
//  - Subtree betas/nums stay LDS-resident across the top phase
//    (sBetaSub/sNumSub + sBetaTop/sNumTop = 108.5 KB < 160 KB/CU)
//    -> the old phase-D subtree-up redo is DELETED.
//  - Final reduction: per-block double partials (plain stores) + grid sync
//    + 1-block reduce -> the 4096-atomicAdd single-line burst is DELETED.
//  - Old phase-C level-3 contribution (64 nodes) distributed to blk%4==0
//    blocks (each already recomputes num(a3) on its path); block 0 keeps
//    only root+lvl1+lvl2 -> block-0 tail ~3x smaller.
// R9 lesson kept: 512-thread blocks (VGPR ~124, no spill); 1024 caps at 64.

#define G 16
#define C 8
#define GC 128
#define SL 5461

__device__ __forceinline__ float grp8_sum(float v) {
  v += __shfl_xor(v, 1);
  v += __shfl_xor(v, 2);
  v += __shfl_xor(v, 4);
  return v;
}

__device__ __forceinline__ void up_lds(int v, int lab, int gi, int g8,
    const float* asp, const float* __restrict__ sm_bT,
    float* sBeta, float* sNum, bool wantNum) {
  int ch0 = 4*v + 1;
  float ub = 0.f;
  #pragma unroll
  for (int l = 0; l < 4; ++l) {
    const float4* bp = (const float4*)(sBeta + (ch0 + l)*GC + g8);
    float4 b0 = bp[0], b1 = bp[1];
    ub += asp[l]*b0.x + asp[4+l]*b0.y + asp[8+l]*b0.z + asp[12+l]*b0.w
        + asp[16+l]*b1.x + asp[20+l]*b1.y + asp[24+l]*b1.z + asp[28+l]*b1.w;
  }
  float tmp = sm_bT[lab*GC + gi] * ub;
  float s = grp8_sum(tmp);
  sBeta[v*GC + gi] = tmp / s;
  if (wantNum) sNum[v*GC + gi] = ub;
}

__device__ __forceinline__ double down_lds(int v, int lab, float e, int gi, int g8,
    const float* asp, const float* aal, const float* lsp,
    const float* __restrict__ log_bT, float* sBeta, const float* sNum) {
  float pe = e / sNum[v*GC + gi];
  int ch0 = 4*v + 1;
  float local = 0.f;
  #pragma unroll
  for (int l = 0; l < 4; ++l) {
    float4* bp = (float4*)(sBeta + (ch0 + l)*GC + g8);
    float4 b0 = bp[0], b1 = bp[1];
    float S = asp[l]*b0.x + asp[4+l]*b0.y + asp[8+l]*b0.z + asp[12+l]*b0.w
            + asp[16+l]*b1.x + asp[20+l]*b1.y + asp[24+l]*b1.z + asp[28+l]*b1.w;
    float A = aal[l]*b0.x + aal[4+l]*b0.y + aal[8+l]*b0.z + aal[12+l]*b0.w
            + aal[16+l]*b1.x + aal[20+l]*b1.y + aal[24+l]*b1.z + aal[28+l]*b1.w;
    float ce = pe * S;
    sBeta[(ch0 + l)*GC + gi] = ce;          // beta slot -> eps
    local += pe*A + ce*lsp[l];
  }
  return (double)local + (double)(e * log_bT[lab*GC + gi]);
}

__global__ __launch_bounds__(512, 1) void fused_kernel(
    const int* __restrict__ t,
    const float* __restrict__ ain, const float* __restrict__ bin,
    const float* __restrict__ piin, const float* __restrict__ spin,
    float* __restrict__ a_sp, float* __restrict__ log_a,
    float* __restrict__ sm_bT, float* __restrict__ log_bT,
    float* __restrict__ sm_piT, float* __restrict__ log_piT,
    float* __restrict__ log_sp, float* __restrict__ betaG,
    double* __restrict__ partial, float* __restrict__ out) {
  cg::grid_group grid = cg::this_grid();

  __shared__ float  sBetaSub[85*GC];        // 42.5 KB  (subtree, persists)
  __shared__ float  sNumSub[21*GC];         // 10.5 KB
  __shared__ float  sBetaTop[85*GC];        // 42.5 KB  (top redundant copy)
  __shared__ float  sNumTop[21*GC];         // 10.5 KB
  __shared__ double sd[64];
  __shared__ double sfin[256];
  __shared__ float  red8[8];

  const int blk = blockIdx.x, tid = threadIdx.x;
  const int gi = tid & 127, g = gi >> 3, i = gi & 7, g8 = g*8, w = tid >> 7; // w 0..3

  // ===== phase 0: setup (softmaxes -> transposed tables) =====
  if (blk < 128) {
    // one (g,c) row of b per block: softmax over 256 labels; halves duplicate
    int row = blk;
    int lab = tid & 255;
    float x = bin[row*256 + lab];
    float m = x;
    #pragma unroll
    for (int off = 32; off; off >>= 1) m = fmaxf(m, __shfl_xor(m, off));
    if ((tid & 63) == 0) red8[tid >> 6] = m;
    __syncthreads();
    m = fmaxf(fmaxf(red8[0], red8[1]), fmaxf(red8[2], red8[3]));
    __syncthreads();
    float e = expf(x - m);
    float ssum = e;
    #pragma unroll
    for (int off = 32; off; off >>= 1) ssum += __shfl_xor(ssum, off);
    if ((tid & 63) == 0) red8[tid >> 6] = ssum;
    __syncthreads();
    ssum = red8[0] + red8[1] + red8[2] + red8[3];
    if (tid < 256) {
      sm_bT[lab*GC + row]  = e / ssum;
      log_bT[lab*GC + row] = (x - m) - logf(ssum);
    }
  } else if (blk == 128) {
    // softmax of a over i (axis=1), times sm_sp -> a_sp; also log(sm_a)
    int col = tid;                          // 0..511
    int gg = col >> 5, jj = (col >> 2) & 7, ll = col & 3;
    float x[8], m = -1e30f;
    #pragma unroll
    for (int ii = 0; ii < 8; ++ii) { x[ii] = ain[gg*256 + ii*32 + jj*4 + ll]; m = fmaxf(m, x[ii]); }
    float ssum = 0.f;
    #pragma unroll
    for (int ii = 0; ii < 8; ++ii) ssum += expf(x[ii] - m);
    float ls = logf(ssum);
    float y0 = spin[gg*4+0], y1 = spin[gg*4+1], y2 = spin[gg*4+2], y3 = spin[gg*4+3];
    float ms = fmaxf(fmaxf(y0, y1), fmaxf(y2, y3));
    float d = expf(y0-ms) + expf(y1-ms) + expf(y2-ms) + expf(y3-ms);
    float spv = expf(spin[gg*4+ll] - ms) / d;
    #pragma unroll
    for (int ii = 0; ii < 8; ++ii) {
      int o2 = gg*256 + ii*32 + jj*4 + ll;
      float smv = expf(x[ii] - m) / ssum;
      a_sp[o2]  = smv * spv;
      log_a[o2] = (x[ii] - m) - ls;
    }
  } else if (blk == 129) {
    if (tid < 64) {
      // softmax of pi over c for each (g,l); transposed [l][g*8+c]
      int gg = tid >> 2, ll = tid & 3;
      float x[8], m = -1e30f;
      #pragma unroll
      for (int c = 0; c < 8; ++c) { x[c] = piin[gg*32 + c*4 + ll]; m = fmaxf(m, x[c]); }
      float ssum = 0.f;
      #pragma unroll
      for (int c = 0; c < 8; ++c) ssum += expf(x[c] - m);
      float ls = logf(ssum);
      #pragma unroll
      for (int c = 0; c < 8; ++c) {
        sm_piT[ll*GC + gg*8 + c]  = expf(x[c] - m) / ssum;
        log_piT[ll*GC + gg*8 + c] = (x[c] - m) - ls;
      }
    } else if (tid < 80) {
      int gg = tid - 64;
      float y[4], m = -1e30f;
      #pragma unroll
      for (int l = 0; l < 4; ++l) { y[l] = spin[gg*4 + l]; m = fmaxf(m, y[l]); }
      float ssum = 0.f;
      #pragma unroll
      for (int l = 0; l < 4; ++l) ssum += expf(y[l] - m);
      float ls = logf(ssum);
      #pragma unroll
      for (int l = 0; l < 4; ++l) log_sp[gg*4 + l] = (y[l] - m) - ls;
    }
  }
  __threadfence();
  grid.sync();                              // tables visible device-wide

  // per-thread transition tables
  float asp[32], aal[32], lsp[4];
  {
    const float4* pa = (const float4*)(a_sp  + g*256 + i*32);
    const float4* pl = (const float4*)(log_a + g*256 + i*32);
    #pragma unroll
    for (int k = 0; k < 8; ++k) {
      float4 va = pa[k], vl = pl[k];
      asp[k*4+0]=va.x; asp[k*4+1]=va.y; asp[k*4+2]=va.z; asp[k*4+3]=va.w;
      aal[k*4+0]=va.x*vl.x; aal[k*4+1]=va.y*vl.y; aal[k*4+2]=va.z*vl.z; aal[k*4+3]=va.w*vl.w;
    }
    #pragma unroll
    for (int l = 0; l < 4; ++l) lsp[l] = log_sp[g*4 + l];
  }

  // ===== phase 1: subtree up (stays resident in sBetaSub/sNumSub) =====
  const int base_leaf = SL + blk*64;
  #pragma unroll
  for (int it = 0; it < 16; ++it) {         // leaves: locals 21..84
    int k = it*4 + w;
    float bt = sm_piT[(k & 3)*GC + gi] * sm_bT[t[(base_leaf + k)*7]*GC + gi];
    float s = grp8_sum(bt);
    sBetaSub[(21 + k)*GC + gi] = bt / s;
  }
  __syncthreads();
  #pragma unroll
  for (int it = 0; it < 4; ++it) {          // level 6: locals 5..20
    int k = it*4 + w;
    up_lds(5 + k, t[(1365 + blk*16 + k)*7], gi, g8, asp, sm_bT, sBetaSub, sNumSub, true);
  }
  __syncthreads();
  up_lds(1 + w, t[(341 + blk*4 + w)*7], gi, g8, asp, sm_bT, sBetaSub, sNumSub, true); // lvl5
  __syncthreads();
  if (tid < 128) {                          // subtree root: local 0
    up_lds(0, t[(85 + blk)*7], gi, g8, asp, sm_bT, sBetaSub, sNumSub, true);
    betaG[(size_t)(85 + blk)*GC + gi] = sBetaSub[gi];
  }
  __threadfence();
  grid.sync();                              // betaG published

  // ===== phase 3: redundant top-up into sBetaTop/sNumTop =====
  #pragma unroll
  for (int it = 0; it < 16; ++it) {         // level 3: nodes 21..84 from betaG
    int k = it*4 + w, u = 21 + k;
    int ch0 = 4*u + 1;                      // = 85 + 4k (subtree roots)
    float ub = 0.f;
    #pragma unroll
    for (int l = 0; l < 4; ++l) {
      const float4* bp = (const float4*)(betaG + (size_t)(ch0 + l)*GC + g8);
      float4 b0 = bp[0], b1 = bp[1];
      ub += asp[l]*b0.x + asp[4+l]*b0.y + asp[8+l]*b0.z + asp[12+l]*b0.w
          + asp[16+l]*b1.x + asp[20+l]*b1.y + asp[24+l]*b1.z + asp[28+l]*b1.w;
    }
    float tmp = sm_bT[t[u*7]*GC + gi] * ub;
    float s = grp8_sum(tmp);
    sBetaTop[u*GC + gi] = tmp / s;          // num for 21..84 NOT stored
  }
  __syncthreads();
  #pragma unroll
  for (int it = 0; it < 4; ++it) {          // level 2: nodes 5..20
    int u = 5 + it*4 + w;
    up_lds(u, t[u*7], gi, g8, asp, sm_bT, sBetaTop, sNumTop, true);
  }
  __syncthreads();
  up_lds(1 + w, t[(1 + w)*7], gi, g8, asp, sm_bT, sBetaTop, sNumTop, true);   // lvl1
  __syncthreads();
  if (tid < 128)                            // root
    up_lds(0, t[0], gi, g8, asp, sm_bT, sBetaTop, sNumTop, true);
  __syncthreads();

  // ===== phase 4: own subtree-root eps via the root path; blk%4==0 also
  //                contributes its level-3 ancestor a3's terms =====
  double acc = 0.0;
  float eRoot = 0.f;
  if (tid < 128) {
    int a1 = 1 + (blk >> 6), a2 = 5 + (blk >> 4), a3 = 21 + (blk >> 2);
    float e = sBetaTop[gi];                 // eps(root) = beta(root)
    int anc[3] = {0, a1, a2};
    int chn[3] = {a1, a2, a3};
    #pragma unroll
    for (int s2 = 0; s2 < 3; ++s2) {        // anc ids 0..20: sNumTop valid
      float pe = e / sNumTop[anc[s2]*GC + gi];
      int l = (chn[s2] - 1) & 3;
      const float4* bp = (const float4*)(sBetaTop + chn[s2]*GC + g8);
      float4 b0 = bp[0], b1 = bp[1];
      float S = asp[l]*b0.x + asp[4+l]*b0.y + asp[8+l]*b0.z + asp[12+l]*b0.w
              + asp[16+l]*b1.x + asp[20+l]*b1.y + asp[24+l]*b1.z + asp[28+l]*b1.w;
      e = pe * S;
    }
    // final step a3 -> own root (85+blk): num(a3) recomputed from betaG
    float Sv[4], Av[4], num3 = 0.f;
    int c30 = 4*a3 + 1;
    #pragma unroll
    for (int l = 0; l < 4; ++l) {
      const float4* bp = (const float4*)(betaG + (size_t)(c30 + l)*GC + g8);
      float4 b0 = bp[0], b1 = bp[1];
      Sv[l] = asp[l]*b0.x + asp[4+l]*b0.y + asp[8+l]*b0.z + asp[12+l]*b0.w
            + asp[16+l]*b1.x + asp[20+l]*b1.y + asp[24+l]*b1.z + asp[28+l]*b1.w;
      num3 += Sv[l];
      Av[l] = aal[l]*b0.x + aal[4+l]*b0.y + aal[8+l]*b0.z + aal[12+l]*b0.w
            + aal[16+l]*b1.x + aal[20+l]*b1.y + aal[24+l]*b1.z + aal[28+l]*b1.w;
    }
    float e3 = e;
    float pe3 = e3 / num3;
    eRoot = pe3 * Sv[blk & 3];
    if ((blk & 3) == 0) {                   // distributed level-3 contribution
      float local = 0.f;
      #pragma unroll
      for (int l = 0; l < 4; ++l) local += pe3*Av[l] + (pe3*Sv[l])*lsp[l];
      acc += (double)local + (double)(e3 * log_bT[t[a3*7]*GC + gi]);
    }
  }

  // ===== phase 5: block 0 only — top-down for nodes 0..20 =====
  if (blk == 0) {
    if (tid < 128)
      acc += down_lds(0, t[0], sBetaTop[gi], gi, g8, asp, aal, lsp, log_bT, sBetaTop, sNumTop);
    __syncthreads();
    {
      int v = 1 + w;
      acc += down_lds(v, t[v*7], sBetaTop[v*GC + gi], gi, g8, asp, aal, lsp, log_bT, sBetaTop, sNumTop);
    }
    __syncthreads();
    #pragma unroll
    for (int it = 0; it < 4; ++it) {
      int v = 5 + it*4 + w;
      acc += down_lds(v, t[v*7], sBetaTop[v*GC + gi], gi, g8, asp, aal, lsp, log_bT, sBetaTop, sNumTop);
    }
  }

  // ===== phase 6: subtree down (sBetaSub/sNumSub retained — no redo) =====
  if (tid < 128)
    acc += down_lds(0, t[(85 + blk)*7], eRoot, gi, g8, asp, aal, lsp, log_bT, sBetaSub, sNumSub);
  __syncthreads();
  {                                         // level 5 (locals 1..4)
    int v = 1 + w;
    acc += down_lds(v, t[(341 + blk*4 + w)*7], sBetaSub[v*GC + gi], gi, g8,
                    asp, aal, lsp, log_bT, sBetaSub, sNumSub);
  }
  __syncthreads();
  #pragma unroll
  for (int it = 0; it < 4; ++it) {          // level 6 (locals 5..20)
    int k = it*4 + w, v = 5 + k;
    acc += down_lds(v, t[(1365 + blk*16 + k)*7], sBetaSub[v*GC + gi], gi, g8,
                    asp, aal, lsp, log_bT, sBetaSub, sNumSub);
  }
  __syncthreads();
  #pragma unroll
  for (int it = 0; it < 16; ++it) {         // leaves: b_lh + pi_lh
    int k = it*4 + w;
    float e = sBetaSub[(21 + k)*GC + gi];
    acc += (double)(e * (log_bT[t[(base_leaf + k)*7]*GC + gi] +
                         log_piT[(k & 3)*GC + gi]));
  }

  // per-block reduction -> double partial (plain store, no atomics)
  acc += __shfl_xor(acc, 1);
  acc += __shfl_xor(acc, 2);
  acc += __shfl_xor(acc, 4);
  if (i == 0) sd[tid >> 3] = acc;           // tid>>3 = w*16 + g (0..63)
  __syncthreads();
  if (tid < 16) partial[blk*16 + tid] = sd[tid] + sd[16 + tid] + sd[32 + tid] + sd[48 + tid];
  __threadfence();
  grid.sync();

  // ===== final: block 0 reduces 256x16 partials -> out =====
  if (blk == 0) {
    if (tid < 256) {
      int gg = tid & 15, ch = tid >> 4;     // 16 chunks x 16 blocks
      const double* p = partial + (size_t)ch*256 + gg;
      double s = 0.0;
      #pragma unroll
      for (int q = 0; q < 16; ++q) s += p[q*16];
      sfin[tid] = s;
    }
    __syncthreads();
    if (tid < 16) {
      double tot = 0.0;
      #pragma unroll
      for (int ch = 0; ch < 16; ++ch) tot += sfin[ch*16 + tid];
      out[tid] = (float)tot;
    }
  }
}

extern "C" void kernel_launch(void* const* d_in, const int* in_sizes, int n_in,
                              void* d_out, int out_size, void* d_ws, size_t ws_size,
                              hipStream_t stream) {
  const int*   t  = (const int*)d_in[0];
  // d_in[1] = t_limits (tree shape is compile-time constant)
  const float* a  = (const float*)d_in[2];
  const float* b  = (const float*)d_in[3];
  const float* pi = (const float*)d_in[4];
  const float* sp = (const float*)d_in[5];
  float* out = (float*)d_out;

  char* wsp = (char*)d_ws;
  size_t off = 0;
  auto carve = [&](size_t bytes) -> void* {
    void* ptr = wsp + off;
    off += (bytes + 255) & ~(size_t)255;
    return ptr;
  };
  float*  a_sp    = (float*)carve((size_t)16*8*8*4*4);
  float*  log_a   = (float*)carve((size_t)16*8*8*4*4);
  float*  sm_bT   = (float*)carve((size_t)256*GC*4);
  float*  log_bT  = (float*)carve((size_t)256*GC*4);
  float*  sm_piT  = (float*)carve((size_t)4*GC*4);
  float*  log_piT = (float*)carve((size_t)4*GC*4);
  float*  log_sp  = (float*)carve((size_t)16*4*4);
  float*  betaG   = (float*)carve((size_t)341*GC*4);   // subtree-root betas
  double* partial = (double*)carve((size_t)256*16*8);  // per-block partials

  void* kargs[] = { (void*)&t, (void*)&a, (void*)&b, (void*)&pi, (void*)&sp,
                    (void*)&a_sp, (void*)&log_a, (void*)&sm_bT, (void*)&log_bT,
                    (void*)&sm_piT, (void*)&log_piT, (void*)&log_sp,
                    (void*)&betaG, (void*)&partial, (void*)&out };
  hipLaunchCooperativeKernel((const void*)fused_kernel, dim3(256), dim3(512),
                             kargs, 0, stream);
}

// Round 2
// 169.598 us; speedup vs baseline: 1.9488x; 1.9488x over previous
//
#include <hip/hip_runtime.h>

// Bottom-up HTMM on a complete 4-ary tree, depth 7 (t_size=21845).
// children(u)=4u+1..4u+4, pos(u)=(u-1)&3; only labels t[u*7] are data.
// prior cancels everywhere (only numbeta = prior*beta_il is used).
//
// R11: setup kernel + ONE cooperative up/down kernel with a HAND-ROLLED
// light barrier (R10 post-mortem: cg::grid.sync costs ~80us each on gfx950,
// 3 syncs = 240us; one device-scope atomic arrive + acquire-load spin is us-scale).
//  - Subtree betas/nums stay LDS-resident across the top phase
//    (sBetaSub/sNumSub + sBetaTop/sNumTop = 108.5 KB < 160 KB/CU)
//    -> no subtree-up redo (old 3-kernel phase D deleted).
//  - Final reduction: per-block double partials (plain stores) + arrival
//    counter; LAST block reduces 256x16 partials and writes out directly
//    -> no atomic burst, no extra barrier, no out zeroing.
//  - Level-3 top contribution distributed to blk%4==0 blocks; block 0 only
//    does nodes 0..20 top-down.
// R9 lesson kept: 512-thread blocks (VGPR ~128, no spill); 1024 caps at 64.

#define G 16
#define C 8
#define GC 128
#define SL 5461

__device__ __forceinline__ float grp8_sum(float v) {
  v += __shfl_xor(v, 1);
  v += __shfl_xor(v, 2);
  v += __shfl_xor(v, 4);
  return v;
}

// light grid barrier: one arrive+spin thread per block, device-scope.
__device__ __forceinline__ void barrier_lite(unsigned* bar, unsigned target) {
  __syncthreads();
  if (threadIdx.x == 0) {
    __threadfence();   // release prior global writes (betaG)
    __hip_atomic_fetch_add(bar, 1u, __ATOMIC_RELEASE, __HIP_MEMORY_SCOPE_AGENT);
    while (__hip_atomic_load(bar, __ATOMIC_ACQUIRE, __HIP_MEMORY_SCOPE_AGENT) < target) {
    }
    __threadfence();   // acquire side for the whole block
  }
  __syncthreads();
}

// ---------------- setup: softmaxes + logs (transposed tables) -------------
__global__ void setup_kernel(const float* __restrict__ ain, const float* __restrict__ bin,
                             const float* __restrict__ piin, const float* __restrict__ spin,
                             float* __restrict__ a_sp, float* __restrict__ log_a,
                             float* __restrict__ sm_bT, float* __restrict__ log_bT,
                             float* __restrict__ sm_piT, float* __restrict__ log_piT,
                             float* __restrict__ log_sp, unsigned* __restrict__ syncws) {
  int blk = blockIdx.x, tid = threadIdx.x;
  if (blk < 16) {
    // softmax over labels (M=256) for b[g][c][:]; write transposed [lab][g*8+c]
    int g = blk;
    __shared__ float red4[4];
    for (int c = 0; c < 8; ++c) {
      int row = g * 8 + c;
      float x = bin[row * 256 + tid];
      float m = x;
      #pragma unroll
      for (int off2 = 32; off2; off2 >>= 1) m = fmaxf(m, __shfl_xor(m, off2));
      if ((tid & 63) == 0) red4[tid >> 6] = m;
      __syncthreads();
      m = fmaxf(fmaxf(red4[0], red4[1]), fmaxf(red4[2], red4[3]));
      __syncthreads();
      float e = expf(x - m);
      float ssum = e;
      #pragma unroll
      for (int off2 = 32; off2; off2 >>= 1) ssum += __shfl_xor(ssum, off2);
      if ((tid & 63) == 0) red4[tid >> 6] = ssum;
      __syncthreads();
      ssum = red4[0] + red4[1] + red4[2] + red4[3];
      __syncthreads();
      sm_bT[tid * GC + row]  = e / ssum;
      log_bT[tid * GC + row] = (x - m) - logf(ssum);
    }
  } else if (blk == 16) {
    // softmax of a over i (axis=1), times sm_sp -> a_sp; also log(sm_a)
    for (int col = tid; col < 512; col += 256) {
      int g = col >> 5, j = (col >> 2) & 7, l = col & 3;
      float x[8], m = -1e30f;
      #pragma unroll
      for (int i = 0; i < 8; ++i) { x[i] = ain[g*256 + i*32 + j*4 + l]; m = fmaxf(m, x[i]); }
      float ssum = 0.f;
      #pragma unroll
      for (int i = 0; i < 8; ++i) ssum += expf(x[i] - m);
      float ls = logf(ssum);
      float y0 = spin[g*4+0], y1 = spin[g*4+1], y2 = spin[g*4+2], y3 = spin[g*4+3];
      float ms = fmaxf(fmaxf(y0, y1), fmaxf(y2, y3));
      float d = expf(y0-ms) + expf(y1-ms) + expf(y2-ms) + expf(y3-ms);
      float spv = expf(spin[g*4+l] - ms) / d;
      #pragma unroll
      for (int i = 0; i < 8; ++i) {
        int o2 = g*256 + i*32 + j*4 + l;
        float smv = expf(x[i] - m) / ssum;
        a_sp[o2]  = smv * spv;
        log_a[o2] = (x[i] - m) - ls;
      }
    }
  } else {
    if (tid < 64) {
      // softmax of pi over c (axis=1) for each (g,l); transposed [l][g*8+c]
      int g = tid >> 2, l = tid & 3;
      float x[8], m = -1e30f;
      #pragma unroll
      for (int c = 0; c < 8; ++c) { x[c] = piin[g*32 + c*4 + l]; m = fmaxf(m, x[c]); }
      float ssum = 0.f;
      #pragma unroll
      for (int c = 0; c < 8; ++c) ssum += expf(x[c] - m);
      float ls = logf(ssum);
      #pragma unroll
      for (int c = 0; c < 8; ++c) {
        sm_piT[l*GC + g*8 + c]  = expf(x[c] - m) / ssum;
        log_piT[l*GC + g*8 + c] = (x[c] - m) - ls;
      }
    } else if (tid < 80) {
      // log softmax of sp over l
      int g = tid - 64;
      float y[4], m = -1e30f;
      #pragma unroll
      for (int l = 0; l < 4; ++l) { y[l] = spin[g*4 + l]; m = fmaxf(m, y[l]); }
      float ssum = 0.f;
      #pragma unroll
      for (int l = 0; l < 4; ++l) ssum += expf(y[l] - m);
      float ls = logf(ssum);
      #pragma unroll
      for (int l = 0; l < 4; ++l) log_sp[g*4 + l] = (y[l] - m) - ls;
    } else if (tid < 82) {
      syncws[tid - 80] = 0u;               // bar, ctr (poisoned 0xAA)
    }
  }
}

// ---------------- LDS bodies (validated rounds 4/5/7/9/10) ----------------
__device__ __forceinline__ void up_lds(int v, int lab, int gi, int g8,
    const float* asp, const float* __restrict__ sm_bT,
    float* sBeta, float* sNum, bool wantNum) {
  int ch0 = 4*v + 1;
  float ub = 0.f;
  #pragma unroll
  for (int l = 0; l < 4; ++l) {
    const float4* bp = (const float4*)(sBeta + (ch0 + l)*GC + g8);
    float4 b0 = bp[0], b1 = bp[1];
    ub += asp[l]*b0.x + asp[4+l]*b0.y + asp[8+l]*b0.z + asp[12+l]*b0.w
        + asp[16+l]*b1.x + asp[20+l]*b1.y + asp[24+l]*b1.z + asp[28+l]*b1.w;
  }
  float tmp = sm_bT[lab*GC + gi] * ub;
  float s = grp8_sum(tmp);
  sBeta[v*GC + gi] = tmp / s;
  if (wantNum) sNum[v*GC + gi] = ub;
}

__device__ __forceinline__ double down_lds(int v, int lab, float e, int gi, int g8,
    const float* asp, const float* aal, const float* lsp,
    const float* __restrict__ log_bT, float* sBeta, const float* sNum) {
  float pe = e / sNum[v*GC + gi];
  int ch0 = 4*v + 1;
  float local = 0.f;
  #pragma unroll
  for (int l = 0; l < 4; ++l) {
    float4* bp = (float4*)(sBeta + (ch0 + l)*GC + g8);
    float4 b0 = bp[0], b1 = bp[1];
    float S = asp[l]*b0.x + asp[4+l]*b0.y + asp[8+l]*b0.z + asp[12+l]*b0.w
            + asp[16+l]*b1.x + asp[20+l]*b1.y + asp[24+l]*b1.z + asp[28+l]*b1.w;
    float A = aal[l]*b0.x + aal[4+l]*b0.y + aal[8+l]*b0.z + aal[12+l]*b0.w
            + aal[16+l]*b1.x + aal[20+l]*b1.y + aal[24+l]*b1.z + aal[28+l]*b1.w;
    float ce = pe * S;
    sBeta[(ch0 + l)*GC + gi] = ce;          // beta slot -> eps
    local += pe*A + ce*lsp[l];
  }
  return (double)local + (double)(e * log_bT[lab*GC + gi]);
}

// ---------------- up + down, one cooperative kernel, one light barrier ----
__global__ __launch_bounds__(512, 1) void updown_kernel(
    const float* __restrict__ a_sp, const float* __restrict__ log_a,
    const float* __restrict__ log_sp, const float* __restrict__ sm_bT,
    const float* __restrict__ log_bT, const float* __restrict__ sm_piT,
    const float* __restrict__ log_piT, const int* __restrict__ t,
    float* __restrict__ betaG, unsigned* __restrict__ bar,
    unsigned* __restrict__ ctr, double* __restrict__ partial,
    float* __restrict__ out) {
  __shared__ float  sBetaSub[85*GC];        // 42.5 KB (subtree, persists)
  __shared__ float  sNumSub[21*GC];         // 10.5 KB
  __shared__ float  sBetaTop[85*GC];        // 42.5 KB (top redundant copy)
  __shared__ float  sNumTop[21*GC];         // 10.5 KB
  __shared__ double sd[64];
  __shared__ double sfin[256];
  __shared__ unsigned lastFlag;

  const int blk = blockIdx.x, tid = threadIdx.x;
  const int gi = tid & 127, g = gi >> 3, i = gi & 7, g8 = g*8, w = tid >> 7; // w 0..3

  // per-thread transition tables
  float asp[32], aal[32], lsp[4];
  {
    const float4* pa = (const float4*)(a_sp  + g*256 + i*32);
    const float4* pl = (const float4*)(log_a + g*256 + i*32);
    #pragma unroll
    for (int k = 0; k < 8; ++k) {
      float4 va = pa[k], vl = pl[k];
      asp[k*4+0]=va.x; asp[k*4+1]=va.y; asp[k*4+2]=va.z; asp[k*4+3]=va.w;
      aal[k*4+0]=va.x*vl.x; aal[k*4+1]=va.y*vl.y; aal[k*4+2]=va.z*vl.z; aal[k*4+3]=va.w*vl.w;
    }
    #pragma unroll
    for (int l = 0; l < 4; ++l) lsp[l] = log_sp[g*4 + l];
  }

  // ===== phase 1: subtree up (stays resident in sBetaSub/sNumSub) =====
  const int base_leaf = SL + blk*64;
  #pragma unroll
  for (int it = 0; it < 16; ++it) {         // leaves: locals 21..84
    int k = it*4 + w;
    float bt = sm_piT[(k & 3)*GC + gi] * sm_bT[t[(base_leaf + k)*7]*GC + gi];
    float s = grp8_sum(bt);
    sBetaSub[(21 + k)*GC + gi] = bt / s;
  }
  __syncthreads();
  #pragma unroll
  for (int it = 0; it < 4; ++it) {          // level 6: locals 5..20
    int k = it*4 + w;
    up_lds(5 + k, t[(1365 + blk*16 + k)*7], gi, g8, asp, sm_bT, sBetaSub, sNumSub, true);
  }
  __syncthreads();
  up_lds(1 + w, t[(341 + blk*4 + w)*7], gi, g8, asp, sm_bT, sBetaSub, sNumSub, true); // lvl5
  __syncthreads();
  if (tid < 128) {                          // subtree root: local 0
    up_lds(0, t[(85 + blk)*7], gi, g8, asp, sm_bT, sBetaSub, sNumSub, true);
    betaG[(size_t)(85 + blk)*GC + gi] = sBetaSub[gi];
  }

  barrier_lite(bar, 256);                   // betaG published device-wide

  // ===== phase 3: redundant top-up into sBetaTop/sNumTop =====
  #pragma unroll
  for (int it = 0; it < 16; ++it) {         // level 3: nodes 21..84 from betaG
    int k = it*4 + w, u = 21 + k;
    int ch0 = 4*u + 1;                      // = 85 + 4k (subtree roots)
    float ub = 0.f;
    #pragma unroll
    for (int l = 0; l < 4; ++l) {
      const float4* bp = (const float4*)(betaG + (size_t)(ch0 + l)*GC + g8);
      float4 b0 = bp[0], b1 = bp[1];
      ub += asp[l]*b0.x + asp[4+l]*b0.y + asp[8+l]*b0.z + asp[12+l]*b0.w
          + asp[16+l]*b1.x + asp[20+l]*b1.y + asp[24+l]*b1.z + asp[28+l]*b1.w;
    }
    float tmp = sm_bT[t[u*7]*GC + gi] * ub;
    float s = grp8_sum(tmp);
    sBetaTop[u*GC + gi] = tmp / s;          // num for 21..84 NOT stored
  }
  __syncthreads();
  #pragma unroll
  for (int it = 0; it < 4; ++it) {          // level 2: nodes 5..20
    int u = 5 + it*4 + w;
    up_lds(u, t[u*7], gi, g8, asp, sm_bT, sBetaTop, sNumTop, true);
  }
  __syncthreads();
  up_lds(1 + w, t[(1 + w)*7], gi, g8, asp, sm_bT, sBetaTop, sNumTop, true);   // lvl1
  __syncthreads();
  if (tid < 128)                            // root
    up_lds(0, t[0], gi, g8, asp, sm_bT, sBetaTop, sNumTop, true);
  __syncthreads();

  // ===== phase 4: own subtree-root eps via the root path; blk%4==0 also
  //                contributes its level-3 ancestor a3's terms =====
  double acc = 0.0;
  float eRoot = 0.f;
  if (tid < 128) {
    int a1 = 1 + (blk >> 6), a2 = 5 + (blk >> 4), a3 = 21 + (blk >> 2);
    float e = sBetaTop[gi];                 // eps(root) = beta(root)
    int anc[3] = {0, a1, a2};
    int chn[3] = {a1, a2, a3};
    #pragma unroll
    for (int s2 = 0; s2 < 3; ++s2) {        // anc ids 0..20: sNumTop valid
      float pe = e / sNumTop[anc[s2]*GC + gi];
      int l = (chn[s2] - 1) & 3;
      const float4* bp = (const float4*)(sBetaTop + chn[s2]*GC + g8);
      float4 b0 = bp[0], b1 = bp[1];
      float S = asp[l]*b0.x + asp[4+l]*b0.y + asp[8+l]*b0.z + asp[12+l]*b0.w
              + asp[16+l]*b1.x + asp[20+l]*b1.y + asp[24+l]*b1.z + asp[28+l]*b1.w;
      e = pe * S;
    }
    // final step a3 -> own root (85+blk): num(a3) recomputed from betaG
    float Sv[4], Av[4], num3 = 0.f;
    int c30 = 4*a3 + 1;
    #pragma unroll
    for (int l = 0; l < 4; ++l) {
      const float4* bp = (const float4*)(betaG + (size_t)(c30 + l)*GC + g8);
      float4 b0 = bp[0], b1 = bp[1];
      Sv[l] = asp[l]*b0.x + asp[4+l]*b0.y + asp[8+l]*b0.z + asp[12+l]*b0.w
            + asp[16+l]*b1.x + asp[20+l]*b1.y + asp[24+l]*b1.z + asp[28+l]*b1.w;
      num3 += Sv[l];
      Av[l] = aal[l]*b0.x + aal[4+l]*b0.y + aal[8+l]*b0.z + aal[12+l]*b0.w
            + aal[16+l]*b1.x + aal[20+l]*b1.y + aal[24+l]*b1.z + aal[28+l]*b1.w;
    }
    float e3 = e;
    float pe3 = e3 / num3;
    eRoot = pe3 * Sv[blk & 3];
    if ((blk & 3) == 0) {                   // distributed level-3 contribution
      float local = 0.f;
      #pragma unroll
      for (int l = 0; l < 4; ++l) local += pe3*Av[l] + (pe3*Sv[l])*lsp[l];
      acc += (double)local + (double)(e3 * log_bT[t[a3*7]*GC + gi]);
    }
  }

  // ===== phase 5: block 0 only — top-down for nodes 0..20 =====
  if (blk == 0) {
    if (tid < 128)
      acc += down_lds(0, t[0], sBetaTop[gi], gi, g8, asp, aal, lsp, log_bT, sBetaTop, sNumTop);
    __syncthreads();
    {
      int v = 1 + w;
      acc += down_lds(v, t[v*7], sBetaTop[v*GC + gi], gi, g8, asp, aal, lsp, log_bT, sBetaTop, sNumTop);
    }
    __syncthreads();
    #pragma unroll
    for (int it = 0; it < 4; ++it) {
      int v = 5 + it*4 + w;
      acc += down_lds(v, t[v*7], sBetaTop[v*GC + gi], gi, g8, asp, aal, lsp, log_bT, sBetaTop, sNumTop);
    }
  }

  // ===== phase 6: subtree down (sBetaSub/sNumSub retained — no redo) =====
  if (tid < 128)
    acc += down_lds(0, t[(85 + blk)*7], eRoot, gi, g8, asp, aal, lsp, log_bT, sBetaSub, sNumSub);
  __syncthreads();
  {                                         // level 5 (locals 1..4)
    int v = 1 + w;
    acc += down_lds(v, t[(341 + blk*4 + w)*7], sBetaSub[v*GC + gi], gi, g8,
                    asp, aal, lsp, log_bT, sBetaSub, sNumSub);
  }
  __syncthreads();
  #pragma unroll
  for (int it = 0; it < 4; ++it) {          // level 6 (locals 5..20)
    int k = it*4 + w, v = 5 + k;
    acc += down_lds(v, t[(1365 + blk*16 + k)*7], sBetaSub[v*GC + gi], gi, g8,
                    asp, aal, lsp, log_bT, sBetaSub, sNumSub);
  }
  __syncthreads();
  #pragma unroll
  for (int it = 0; it < 16; ++it) {         // leaves: b_lh + pi_lh
    int k = it*4 + w;
    float e = sBetaSub[(21 + k)*GC + gi];
    acc += (double)(e * (log_bT[t[(base_leaf + k)*7]*GC + gi] +
                         log_piT[(k & 3)*GC + gi]));
  }

  // per-block reduction -> double partial (plain stores, no atomics)
  acc += __shfl_xor(acc, 1);
  acc += __shfl_xor(acc, 2);
  acc += __shfl_xor(acc, 4);
  if (i == 0) sd[tid >> 3] = acc;           // tid>>3 = w*16 + g (0..63)
  __syncthreads();
  if (tid < 16) partial[blk*16 + tid] = sd[tid] + sd[16 + tid] + sd[32 + tid] + sd[48 + tid];
  __syncthreads();

  // arrival counter; LAST block reduces all partials and writes out
  if (tid == 0) {
    __threadfence();                        // publish partials
    unsigned old = __hip_atomic_fetch_add(ctr, 1u, __ATOMIC_ACQ_REL, __HIP_MEMORY_SCOPE_AGENT);
    lastFlag = (old == 255u);
    if (lastFlag) __threadfence();          // acquire all blocks' partials
  }
  __syncthreads();
  if (lastFlag) {
    if (tid < 256) {
      int gg = tid & 15, ch = tid >> 4;     // 16 chunks x 16 blocks
      const double* p = partial + (size_t)ch*256 + gg;
      double s = 0.0;
      #pragma unroll
      for (int q = 0; q < 16; ++q) s += p[q*16];
      sfin[tid] = s;
    }
    __syncthreads();
    if (tid < 16) {
      double tot = 0.0;
      #pragma unroll
      for (int ch = 0; ch < 16; ++ch) tot += sfin[ch*16 + tid];
      out[tid] = (float)tot;
    }
  }
}

extern "C" void kernel_launch(void* const* d_in, const int* in_sizes, int n_in,
                              void* d_out, int out_size, void* d_ws, size_t ws_size,
                              hipStream_t stream) {
  const int*   t  = (const int*)d_in[0];
  // d_in[1] = t_limits (tree shape is compile-time constant)
  const float* a  = (const float*)d_in[2];
  const float* b  = (const float*)d_in[3];
  const float* pi = (const float*)d_in[4];
  const float* sp = (const float*)d_in[5];
  float* out = (float*)d_out;

  char* wsp = (char*)d_ws;
  size_t off = 0;
  auto carve = [&](size_t bytes) -> void* {
    void* ptr = wsp + off;
    off += (bytes + 255) & ~(size_t)255;
    return ptr;
  };
  float*    a_sp    = (float*)carve((size_t)16*8*8*4*4);
  float*    log_a   = (float*)carve((size_t)16*8*8*4*4);
  float*    sm_bT   = (float*)carve((size_t)256*GC*4);
  float*    log_bT  = (float*)carve((size_t)256*GC*4);
  float*    sm_piT  = (float*)carve((size_t)4*GC*4);
  float*    log_piT = (float*)carve((size_t)4*GC*4);
  float*    log_sp  = (float*)carve((size_t)16*4*4);
  float*    betaG   = (float*)carve((size_t)341*GC*4);   // subtree-root betas
  double*   partial = (double*)carve((size_t)256*16*8);  // per-block partials
  unsigned* syncws  = (unsigned*)carve((size_t)2*4);     // [0]=bar, [1]=ctr
  unsigned* bar = syncws;
  unsigned* ctr = syncws + 1;

  setup_kernel<<<18, 256, 0, stream>>>(a, b, pi, sp, a_sp, log_a, sm_bT, log_bT,
                                       sm_piT, log_piT, log_sp, syncws);

  void* kargs[] = { (void*)&a_sp, (void*)&log_a, (void*)&log_sp, (void*)&sm_bT,
                    (void*)&log_bT, (void*)&sm_piT, (void*)&log_piT, (void*)&t,
                    (void*)&betaG, (void*)&bar, (void*)&ctr, (void*)&partial,
                    (void*)&out };
  hipLaunchCooperativeKernel((const void*)updown_kernel, dim3(256), dim3(512),
                             kargs, 0, stream);
}

// Round 3
// 111.048 us; speedup vs baseline: 2.9763x; 1.5272x over previous
//
#include <hip/hip_runtime.h>

// Bottom-up HTMM on a complete 4-ary tree, depth 7 (t_size=21845).
// children(u)=4u+1..4u+4, pos(u)=(u-1)&3; only labels t[u*7] are data.
// prior cancels everywhere (only numbeta = prior*beta_il is used).
//
// R12: back to the verified 3-kernel structure (kernel boundary = the only
// cheap grid barrier on gfx950; R10/R11 measured grid.sync ~80us and a
// hand-rolled spin ~55us — both dominated by cross-XCD coherence traffic).
// Kept from R11 (both verified correct there):
//  - partial[256*16] + one ACQ_REL arrival fetch_add per block; LAST block
//    reduces and writes out directly. Replaces R0's 4096 float atomicAdds
//    onto one 64B line (~15-20us serialized burst at the home L2 bank).
//  - level-3 top contribution distributed to blk%4==0 blocks; block 0's
//    serial top-down tail is only nodes 0..20.
// R9 lesson kept: 512-thread blocks (VGPR ~128, no spill); 1024 caps at 64.

#define G 16
#define C 8
#define GC 128
#define TSIZE 21845
#define SL 5461

__device__ __forceinline__ float grp8_sum(float v) {
  v += __shfl_xor(v, 1);
  v += __shfl_xor(v, 2);
  v += __shfl_xor(v, 4);
  return v;
}

// ---------------- setup: softmaxes + logs (transposed tables) -------------
__global__ void setup_kernel(const float* __restrict__ ain, const float* __restrict__ bin,
                             const float* __restrict__ piin, const float* __restrict__ spin,
                             float* __restrict__ a_sp, float* __restrict__ log_a,
                             float* __restrict__ sm_bT, float* __restrict__ log_bT,
                             float* __restrict__ sm_piT, float* __restrict__ log_piT,
                             float* __restrict__ log_sp, unsigned* __restrict__ ctr) {
  int blk = blockIdx.x, tid = threadIdx.x;
  if (blk < 16) {
    // softmax over labels (M=256) for b[g][c][:]; write transposed [lab][g*8+c]
    int g = blk;
    __shared__ float red4[4];
    for (int c = 0; c < 8; ++c) {
      int row = g * 8 + c;
      float x = bin[row * 256 + tid];
      float m = x;
      #pragma unroll
      for (int off2 = 32; off2; off2 >>= 1) m = fmaxf(m, __shfl_xor(m, off2));
      if ((tid & 63) == 0) red4[tid >> 6] = m;
      __syncthreads();
      m = fmaxf(fmaxf(red4[0], red4[1]), fmaxf(red4[2], red4[3]));
      __syncthreads();
      float e = expf(x - m);
      float ssum = e;
      #pragma unroll
      for (int off2 = 32; off2; off2 >>= 1) ssum += __shfl_xor(ssum, off2);
      if ((tid & 63) == 0) red4[tid >> 6] = ssum;
      __syncthreads();
      ssum = red4[0] + red4[1] + red4[2] + red4[3];
      __syncthreads();
      sm_bT[tid * GC + row]  = e / ssum;
      log_bT[tid * GC + row] = (x - m) - logf(ssum);
    }
  } else if (blk == 16) {
    // softmax of a over i (axis=1), times sm_sp -> a_sp; also log(sm_a)
    for (int col = tid; col < 512; col += 256) {
      int g = col >> 5, j = (col >> 2) & 7, l = col & 3;
      float x[8], m = -1e30f;
      #pragma unroll
      for (int i = 0; i < 8; ++i) { x[i] = ain[g*256 + i*32 + j*4 + l]; m = fmaxf(m, x[i]); }
      float ssum = 0.f;
      #pragma unroll
      for (int i = 0; i < 8; ++i) ssum += expf(x[i] - m);
      float ls = logf(ssum);
      float y0 = spin[g*4+0], y1 = spin[g*4+1], y2 = spin[g*4+2], y3 = spin[g*4+3];
      float ms = fmaxf(fmaxf(y0, y1), fmaxf(y2, y3));
      float d = expf(y0-ms) + expf(y1-ms) + expf(y2-ms) + expf(y3-ms);
      float spv = expf(spin[g*4+l] - ms) / d;
      #pragma unroll
      for (int i = 0; i < 8; ++i) {
        int o2 = g*256 + i*32 + j*4 + l;
        float smv = expf(x[i] - m) / ssum;
        a_sp[o2]  = smv * spv;
        log_a[o2] = (x[i] - m) - ls;
      }
    }
  } else {
    if (tid < 64) {
      // softmax of pi over c (axis=1) for each (g,l); transposed [l][g*8+c]
      int g = tid >> 2, l = tid & 3;
      float x[8], m = -1e30f;
      #pragma unroll
      for (int c = 0; c < 8; ++c) { x[c] = piin[g*32 + c*4 + l]; m = fmaxf(m, x[c]); }
      float ssum = 0.f;
      #pragma unroll
      for (int c = 0; c < 8; ++c) ssum += expf(x[c] - m);
      float ls = logf(ssum);
      #pragma unroll
      for (int c = 0; c < 8; ++c) {
        sm_piT[l*GC + g*8 + c]  = expf(x[c] - m) / ssum;
        log_piT[l*GC + g*8 + c] = (x[c] - m) - ls;
      }
    } else if (tid < 80) {
      // log softmax of sp over l
      int g = tid - 64;
      float y[4], m = -1e30f;
      #pragma unroll
      for (int l = 0; l < 4; ++l) { y[l] = spin[g*4 + l]; m = fmaxf(m, y[l]); }
      float ssum = 0.f;
      #pragma unroll
      for (int l = 0; l < 4; ++l) ssum += expf(y[l] - m);
      float ls = logf(ssum);
      #pragma unroll
      for (int l = 0; l < 4; ++l) log_sp[g*4 + l] = (y[l] - m) - ls;
    } else if (tid == 80) {
      *ctr = 0u;                           // arrival counter (poisoned 0xAA)
    }
  }
}

// ---------------- LDS bodies (validated rounds 4/5/7/9/11) ----------------
__device__ __forceinline__ void up_lds(int v, int lab, int gi, int g8,
    const float* asp, const float* __restrict__ sm_bT,
    float* sBeta, float* sNum, bool wantNum) {
  int ch0 = 4*v + 1;
  float ub = 0.f;
  #pragma unroll
  for (int l = 0; l < 4; ++l) {
    const float4* bp = (const float4*)(sBeta + (ch0 + l)*GC + g8);
    float4 b0 = bp[0], b1 = bp[1];
    ub += asp[l]*b0.x + asp[4+l]*b0.y + asp[8+l]*b0.z + asp[12+l]*b0.w
        + asp[16+l]*b1.x + asp[20+l]*b1.y + asp[24+l]*b1.z + asp[28+l]*b1.w;
  }
  float tmp = sm_bT[lab*GC + gi] * ub;
  float s = grp8_sum(tmp);
  sBeta[v*GC + gi] = tmp / s;
  if (wantNum) sNum[v*GC + gi] = ub;
}

__device__ __forceinline__ double down_lds(int v, int lab, float e, int gi, int g8,
    const float* asp, const float* aal, const float* lsp,
    const float* __restrict__ log_bT, float* sBeta, const float* sNum) {
  float pe = e / sNum[v*GC + gi];
  int ch0 = 4*v + 1;
  float local = 0.f;
  #pragma unroll
  for (int l = 0; l < 4; ++l) {
    float4* bp = (float4*)(sBeta + (ch0 + l)*GC + g8);
    float4 b0 = bp[0], b1 = bp[1];
    float S = asp[l]*b0.x + asp[4+l]*b0.y + asp[8+l]*b0.z + asp[12+l]*b0.w
            + asp[16+l]*b1.x + asp[20+l]*b1.y + asp[24+l]*b1.z + asp[28+l]*b1.w;
    float A = aal[l]*b0.x + aal[4+l]*b0.y + aal[8+l]*b0.z + aal[12+l]*b0.w
            + aal[16+l]*b1.x + aal[20+l]*b1.y + aal[24+l]*b1.z + aal[28+l]*b1.w;
    float ce = pe * S;
    sBeta[(ch0 + l)*GC + gi] = ce;          // beta slot -> eps
    local += pe*A + ce*lsp[l];
  }
  return (double)local + (double)(e * log_bT[lab*GC + gi]);
}

// ---------------- up: 256 subtrees in LDS, write only root betas ----------
__global__ __launch_bounds__(512, 1) void up_kernel(
    const float* __restrict__ a_sp, const float* __restrict__ sm_bT,
    const float* __restrict__ sm_piT, const int* __restrict__ t,
    float* __restrict__ betaG) {
  __shared__ float sBeta[85*GC];            // 42.5 KB
  const int blk = blockIdx.x, tid = threadIdx.x;
  const int gi = tid & 127, g = gi >> 3, i = gi & 7, g8 = g*8, w = tid >> 7; // w 0..3
  float asp[32];
  {
    const float4* pa = (const float4*)(a_sp + g*256 + i*32);
    #pragma unroll
    for (int q = 0; q < 8; ++q) {
      float4 v = pa[q];
      asp[q*4+0]=v.x; asp[q*4+1]=v.y; asp[q*4+2]=v.z; asp[q*4+3]=v.w;
    }
  }
  const int base_leaf = SL + blk*64;
  #pragma unroll
  for (int it = 0; it < 16; ++it) {         // leaves: locals 21..84
    int k = it*4 + w;
    float bt = sm_piT[(k & 3)*GC + gi] * sm_bT[t[(base_leaf + k)*7]*GC + gi];
    float s = grp8_sum(bt);
    sBeta[(21 + k)*GC + gi] = bt / s;
  }
  __syncthreads();
  #pragma unroll
  for (int it = 0; it < 4; ++it) {          // level 6: locals 5..20
    int k = it*4 + w;
    up_lds(5 + k, t[(1365 + blk*16 + k)*7], gi, g8, asp, sm_bT, sBeta, nullptr, false);
  }
  __syncthreads();
  up_lds(1 + w, t[(341 + blk*4 + w)*7], gi, g8, asp, sm_bT, sBeta, nullptr, false); // lvl5
  __syncthreads();
  if (tid < 128) {                          // subtree root: local 0
    up_lds(0, t[(85 + blk)*7], gi, g8, asp, sm_bT, sBeta, nullptr, false);
    betaG[(size_t)(85 + blk)*GC + gi] = sBeta[gi];   // plain store; boundary flushes
  }
}

// ---------------- downall: redundant top + own path + subtree down --------
__global__ __launch_bounds__(512, 1) void downall_kernel(
    const float* __restrict__ a_sp, const float* __restrict__ log_a,
    const float* __restrict__ log_sp, const float* __restrict__ sm_bT,
    const float* __restrict__ log_bT, const float* __restrict__ sm_piT,
    const float* __restrict__ log_piT, const int* __restrict__ t,
    const float* __restrict__ betaG, unsigned* __restrict__ ctr,
    double* __restrict__ partial, float* __restrict__ out) {
  __shared__ float  sBeta[85*GC];           // top first, then subtree (42.5 KB)
  __shared__ float  sNum[21*GC];            // ids 0..20 ONLY (10.5 KB)
  __shared__ float  sEps[GC];               // own subtree-root eps
  __shared__ double sd[64];
  __shared__ double sfin[256];
  __shared__ unsigned lastFlag;
  const int blk = blockIdx.x, tid = threadIdx.x;
  const int gi = tid & 127, g = gi >> 3, i = gi & 7, g8 = g*8, w = tid >> 7; // w 0..3
  float asp[32], aal[32], lsp[4];
  {
    const float4* pa = (const float4*)(a_sp  + g*256 + i*32);
    const float4* pl = (const float4*)(log_a + g*256 + i*32);
    #pragma unroll
    for (int k = 0; k < 8; ++k) {
      float4 va = pa[k], vl = pl[k];
      asp[k*4+0]=va.x; asp[k*4+1]=va.y; asp[k*4+2]=va.z; asp[k*4+3]=va.w;
      aal[k*4+0]=va.x*vl.x; aal[k*4+1]=va.y*vl.y; aal[k*4+2]=va.z*vl.z; aal[k*4+3]=va.w*vl.w;
    }
    #pragma unroll
    for (int l = 0; l < 4; ++l) lsp[l] = log_sp[g*4 + l];
  }

  // ===== phase A: top-up in LDS (nodes 0..84; node id == LDS slot) =====
  #pragma unroll
  for (int it = 0; it < 16; ++it) {         // level 3: 64 nodes, global children
    int k = it*4 + w, u = 21 + k;
    int ch0 = 4*u + 1;                      // = 85 + 4k (subtree roots)
    float ub = 0.f;
    #pragma unroll
    for (int l = 0; l < 4; ++l) {
      const float4* bp = (const float4*)(betaG + (size_t)(ch0 + l)*GC + g8);
      float4 b0 = bp[0], b1 = bp[1];
      ub += asp[l]*b0.x + asp[4+l]*b0.y + asp[8+l]*b0.z + asp[12+l]*b0.w
          + asp[16+l]*b1.x + asp[20+l]*b1.y + asp[24+l]*b1.z + asp[28+l]*b1.w;
    }
    float tmp = sm_bT[t[u*7]*GC + gi] * ub;
    float s = grp8_sum(tmp);
    sBeta[u*GC + gi] = tmp / s;             // numbeta for 21..84 NOT stored
  }
  __syncthreads();
  #pragma unroll
  for (int it = 0; it < 4; ++it) {          // level 2: nodes 5..20
    int u = 5 + it*4 + w;
    up_lds(u, t[u*7], gi, g8, asp, sm_bT, sBeta, sNum, true);
  }
  __syncthreads();
  up_lds(1 + w, t[(1 + w)*7], gi, g8, asp, sm_bT, sBeta, sNum, true);   // lvl1
  __syncthreads();
  if (tid < 128)                            // root
    up_lds(0, t[0], gi, g8, asp, sm_bT, sBeta, sNum, true);
  __syncthreads();

  // ===== phase B: own subtree-root eps via the 4-step root path; =====
  // ===== blk%4==0 also contributes its level-3 ancestor a3's terms =====
  double acc = 0.0;
  if (tid < 128) {
    int a1 = 1 + (blk >> 6), a2 = 5 + (blk >> 4), a3 = 21 + (blk >> 2);
    float e = sBeta[gi];                    // eps(root) = beta(root)
    int anc[3] = {0, a1, a2};
    int chn[3] = {a1, a2, a3};
    #pragma unroll
    for (int s2 = 0; s2 < 3; ++s2) {        // anc ids 0..20: sNum valid
      float pe = e / sNum[anc[s2]*GC + gi];
      int l = (chn[s2] - 1) & 3;
      const float4* bp = (const float4*)(sBeta + chn[s2]*GC + g8);
      float4 b0 = bp[0], b1 = bp[1];
      float S = asp[l]*b0.x + asp[4+l]*b0.y + asp[8+l]*b0.z + asp[12+l]*b0.w
              + asp[16+l]*b1.x + asp[20+l]*b1.y + asp[24+l]*b1.z + asp[28+l]*b1.w;
      e = pe * S;
    }
    // final step a3 -> own root (85+blk): num(a3)/Sv/Av from betaG
    float Sv[4], Av[4], num3 = 0.f;
    int c30 = 4*a3 + 1;
    #pragma unroll
    for (int l = 0; l < 4; ++l) {
      const float4* bp = (const float4*)(betaG + (size_t)(c30 + l)*GC + g8);
      float4 b0 = bp[0], b1 = bp[1];
      Sv[l] = asp[l]*b0.x + asp[4+l]*b0.y + asp[8+l]*b0.z + asp[12+l]*b0.w
            + asp[16+l]*b1.x + asp[20+l]*b1.y + asp[24+l]*b1.z + asp[28+l]*b1.w;
      num3 += Sv[l];
      Av[l] = aal[l]*b0.x + aal[4+l]*b0.y + aal[8+l]*b0.z + aal[12+l]*b0.w
            + aal[16+l]*b1.x + aal[20+l]*b1.y + aal[24+l]*b1.z + aal[28+l]*b1.w;
    }
    float e3 = e;
    float pe3 = e3 / num3;
    sEps[gi] = pe3 * Sv[blk & 3];
    if ((blk & 3) == 0) {                   // distributed level-3 contribution
      float local = 0.f;
      #pragma unroll
      for (int l = 0; l < 4; ++l) local += pe3*Av[l] + (pe3*Sv[l])*lsp[l];
      acc += (double)local + (double)(e3 * log_bT[t[a3*7]*GC + gi]);
    }
  }
  __syncthreads();

  // ===== phase C: block 0 only — top-down for nodes 0..20 =====
  if (blk == 0) {
    if (tid < 128)
      acc += down_lds(0, t[0], sBeta[gi], gi, g8, asp, aal, lsp, log_bT, sBeta, sNum);
    __syncthreads();
    {
      int v = 1 + w;
      acc += down_lds(v, t[v*7], sBeta[v*GC + gi], gi, g8, asp, aal, lsp, log_bT, sBeta, sNum);
    }
    __syncthreads();
    #pragma unroll
    for (int it = 0; it < 4; ++it) {
      int v = 5 + it*4 + w;
      acc += down_lds(v, t[v*7], sBeta[v*GC + gi], gi, g8, asp, aal, lsp, log_bT, sBeta, sNum);
    }
    __syncthreads();                        // protect sBeta reuse below
  }

  // ===== phase D: subtree-up redo (overwrites sBeta/sNum) =====
  const int base_leaf = SL + blk*64;
  #pragma unroll
  for (int it = 0; it < 16; ++it) {
    int k = it*4 + w;
    float bt = sm_piT[(k & 3)*GC + gi] * sm_bT[t[(base_leaf + k)*7]*GC + gi];
    float s = grp8_sum(bt);
    sBeta[(21 + k)*GC + gi] = bt / s;
  }
  __syncthreads();
  #pragma unroll
  for (int it = 0; it < 4; ++it) {
    int k = it*4 + w;
    up_lds(5 + k, t[(1365 + blk*16 + k)*7], gi, g8, asp, sm_bT, sBeta, sNum, true);
  }
  __syncthreads();
  up_lds(1 + w, t[(341 + blk*4 + w)*7], gi, g8, asp, sm_bT, sBeta, sNum, true);  // lvl5
  __syncthreads();

  // ===== phase E: subtree down + fused per-block reduction =====
  if (tid < 128) {
    up_lds(0, t[(85 + blk)*7], gi, g8, asp, sm_bT, sBeta, sNum, true);   // root numbeta
    acc += down_lds(0, t[(85 + blk)*7], sEps[gi], gi, g8, asp, aal, lsp,
                    log_bT, sBeta, sNum);
  }
  __syncthreads();
  {                                         // level 5 (locals 1..4)
    int v = 1 + w;
    acc += down_lds(v, t[(341 + blk*4 + w)*7], sBeta[v*GC + gi], gi, g8,
                    asp, aal, lsp, log_bT, sBeta, sNum);
  }
  __syncthreads();
  #pragma unroll
  for (int it = 0; it < 4; ++it) {          // level 6 (locals 5..20)
    int k = it*4 + w, v = 5 + k;
    acc += down_lds(v, t[(1365 + blk*16 + k)*7], sBeta[v*GC + gi], gi, g8,
                    asp, aal, lsp, log_bT, sBeta, sNum);
  }
  __syncthreads();
  #pragma unroll
  for (int it = 0; it < 16; ++it) {         // leaves: b_lh + pi_lh
    int k = it*4 + w;
    float e = sBeta[(21 + k)*GC + gi];
    acc += (double)(e * (log_bT[t[(base_leaf + k)*7]*GC + gi] +
                         log_piT[(k & 3)*GC + gi]));
  }

  // per-block reduction -> double partial (plain stores, no atomic burst)
  acc += __shfl_xor(acc, 1);
  acc += __shfl_xor(acc, 2);
  acc += __shfl_xor(acc, 4);
  if (i == 0) sd[tid >> 3] = acc;           // tid>>3 = w*16 + g (0..63)
  __syncthreads();
  if (tid < 16) partial[blk*16 + tid] = sd[tid] + sd[16 + tid] + sd[32 + tid] + sd[48 + tid];
  __syncthreads();

  // one ACQ_REL arrival per block; LAST block reduces 256x16 and writes out
  if (tid == 0) {
    unsigned old = __hip_atomic_fetch_add(ctr, 1u, __ATOMIC_ACQ_REL,
                                          __HIP_MEMORY_SCOPE_AGENT);
    lastFlag = (old == 255u);
  }
  __syncthreads();
  if (lastFlag) {
    if (tid < 256) {
      int gg = tid & 15, ch = tid >> 4;     // 16 chunks x 16 blocks
      const double* p = partial + (size_t)ch*256 + gg;
      double s = 0.0;
      #pragma unroll
      for (int q = 0; q < 16; ++q) s += p[q*16];
      sfin[tid] = s;
    }
    __syncthreads();
    if (tid < 16) {
      double tot = 0.0;
      #pragma unroll
      for (int ch = 0; ch < 16; ++ch) tot += sfin[ch*16 + tid];
      out[tid] = (float)tot;
    }
  }
}

extern "C" void kernel_launch(void* const* d_in, const int* in_sizes, int n_in,
                              void* d_out, int out_size, void* d_ws, size_t ws_size,
                              hipStream_t stream) {
  const int*   t  = (const int*)d_in[0];
  // d_in[1] = t_limits (tree shape is compile-time constant)
  const float* a  = (const float*)d_in[2];
  const float* b  = (const float*)d_in[3];
  const float* pi = (const float*)d_in[4];
  const float* sp = (const float*)d_in[5];
  float* out = (float*)d_out;

  char* w = (char*)d_ws;
  size_t off = 0;
  auto carve = [&](size_t bytes) -> void* {
    void* ptr = w + off;
    off += (bytes + 255) & ~(size_t)255;
    return ptr;
  };
  float*    a_sp    = (float*)carve((size_t)16*8*8*4*4);
  float*    log_a   = (float*)carve((size_t)16*8*8*4*4);
  float*    sm_bT   = (float*)carve((size_t)256*GC*4);
  float*    log_bT  = (float*)carve((size_t)256*GC*4);
  float*    sm_piT  = (float*)carve((size_t)4*GC*4);
  float*    log_piT = (float*)carve((size_t)4*GC*4);
  float*    log_sp  = (float*)carve((size_t)16*4*4);
  float*    betaG   = (float*)carve((size_t)341*GC*4);   // subtree-root betas
  double*   partial = (double*)carve((size_t)256*16*8);  // per-block partials
  unsigned* ctr     = (unsigned*)carve((size_t)4);       // arrival counter

  setup_kernel<<<18, 256, 0, stream>>>(a, b, pi, sp, a_sp, log_a, sm_bT, log_bT,
                                       sm_piT, log_piT, log_sp, ctr);
  up_kernel<<<256, 512, 0, stream>>>(a_sp, sm_bT, sm_piT, t, betaG);
  downall_kernel<<<256, 512, 0, stream>>>(a_sp, log_a, log_sp, sm_bT, log_bT,
                                          sm_piT, log_piT, t, betaG, ctr,
                                          partial, out);
}

// Round 4
// 107.098 us; speedup vs baseline: 3.0861x; 1.0369x over previous
//
#include <hip/hip_runtime.h>

// Bottom-up HTMM on a complete 4-ary tree, depth 7 (t_size=21845).
// children(u)=4u+1..4u+4, pos(u)=(u-1)&3; only labels t[u*7] are data.
// prior cancels everywhere (only numbeta = prior*beta_il is used).
//
// R13: 3-kernel structure (kernel boundary = only cheap grid barrier on
// gfx950; R10/R11 measured grid.sync ~80us, hand spin ~55us — cross-XCD
// coherence). Changes vs R12, all bit-identical numerics:
//  - up_kernel now stores the FULL subtree state (beta 85 rows + num 21
//    rows = 53 KB/block) to betaS/numS; downall's phase-D subtree-up redo
//    (16 leaf steps + 21 LDS matvecs + 4 barriers) becomes a bulk
//    global->LDS copy (~6 float4/thread). Reloaded bits == recomputed bits.
//  - setup parallelized: one b-row per block (128 blocks) instead of 16
//    blocks x 8-row serial loop (32-barrier chain); ~4us -> ~1.5us.
//  - phase E root up_lds dropped (root beta/num reloaded like the rest).
// Kept from R12: partial[] + one ACQ_REL arrival per block, LAST block
// reduces; distributed level-3 contribution (blk%4==0); block 0 top-down
// only nodes 0..20. R9 lesson: 512-thread blocks (VGPR ~128, no spill).

#define G 16
#define C 8
#define GC 128
#define TSIZE 21845
#define SL 5461

__device__ __forceinline__ float grp8_sum(float v) {
  v += __shfl_xor(v, 1);
  v += __shfl_xor(v, 2);
  v += __shfl_xor(v, 4);
  return v;
}

// ---------------- setup: softmaxes + logs (transposed tables) -------------
// grid 130 x 256: blocks 0..127 one b-row each; 128 = a/sp; 129 = pi/sp/ctr.
__global__ void setup_kernel(const float* __restrict__ ain, const float* __restrict__ bin,
                             const float* __restrict__ piin, const float* __restrict__ spin,
                             float* __restrict__ a_sp, float* __restrict__ log_a,
                             float* __restrict__ sm_bT, float* __restrict__ log_bT,
                             float* __restrict__ sm_piT, float* __restrict__ log_piT,
                             float* __restrict__ log_sp, unsigned* __restrict__ ctr) {
  int blk = blockIdx.x, tid = threadIdx.x;
  if (blk < 128) {
    // softmax over labels (M=256) for one row (g,c); write transposed [lab][row]
    __shared__ float red4[4];
    int row = blk;                       // g*8 + c
    float x = bin[row * 256 + tid];      // tid = lab
    float m = x;
    #pragma unroll
    for (int off2 = 32; off2; off2 >>= 1) m = fmaxf(m, __shfl_xor(m, off2));
    if ((tid & 63) == 0) red4[tid >> 6] = m;
    __syncthreads();
    m = fmaxf(fmaxf(red4[0], red4[1]), fmaxf(red4[2], red4[3]));
    __syncthreads();
    float e = expf(x - m);
    float ssum = e;
    #pragma unroll
    for (int off2 = 32; off2; off2 >>= 1) ssum += __shfl_xor(ssum, off2);
    if ((tid & 63) == 0) red4[tid >> 6] = ssum;
    __syncthreads();
    ssum = red4[0] + red4[1] + red4[2] + red4[3];
    sm_bT[tid * GC + row]  = e / ssum;
    log_bT[tid * GC + row] = (x - m) - logf(ssum);
  } else if (blk == 128) {
    // softmax of a over i (axis=1), times sm_sp -> a_sp; also log(sm_a)
    for (int col = tid; col < 512; col += 256) {
      int g = col >> 5, j = (col >> 2) & 7, l = col & 3;
      float x[8], m = -1e30f;
      #pragma unroll
      for (int i = 0; i < 8; ++i) { x[i] = ain[g*256 + i*32 + j*4 + l]; m = fmaxf(m, x[i]); }
      float ssum = 0.f;
      #pragma unroll
      for (int i = 0; i < 8; ++i) ssum += expf(x[i] - m);
      float ls = logf(ssum);
      float y0 = spin[g*4+0], y1 = spin[g*4+1], y2 = spin[g*4+2], y3 = spin[g*4+3];
      float ms = fmaxf(fmaxf(y0, y1), fmaxf(y2, y3));
      float d = expf(y0-ms) + expf(y1-ms) + expf(y2-ms) + expf(y3-ms);
      float spv = expf(spin[g*4+l] - ms) / d;
      #pragma unroll
      for (int i = 0; i < 8; ++i) {
        int o2 = g*256 + i*32 + j*4 + l;
        float smv = expf(x[i] - m) / ssum;
        a_sp[o2]  = smv * spv;
        log_a[o2] = (x[i] - m) - ls;
      }
    }
  } else {
    if (tid < 64) {
      // softmax of pi over c (axis=1) for each (g,l); transposed [l][g*8+c]
      int g = tid >> 2, l = tid & 3;
      float x[8], m = -1e30f;
      #pragma unroll
      for (int c = 0; c < 8; ++c) { x[c] = piin[g*32 + c*4 + l]; m = fmaxf(m, x[c]); }
      float ssum = 0.f;
      #pragma unroll
      for (int c = 0; c < 8; ++c) ssum += expf(x[c] - m);
      float ls = logf(ssum);
      #pragma unroll
      for (int c = 0; c < 8; ++c) {
        sm_piT[l*GC + g*8 + c]  = expf(x[c] - m) / ssum;
        log_piT[l*GC + g*8 + c] = (x[c] - m) - ls;
      }
    } else if (tid < 80) {
      // log softmax of sp over l
      int g = tid - 64;
      float y[4], m = -1e30f;
      #pragma unroll
      for (int l = 0; l < 4; ++l) { y[l] = spin[g*4 + l]; m = fmaxf(m, y[l]); }
      float ssum = 0.f;
      #pragma unroll
      for (int l = 0; l < 4; ++l) ssum += expf(y[l] - m);
      float ls = logf(ssum);
      #pragma unroll
      for (int l = 0; l < 4; ++l) log_sp[g*4 + l] = (y[l] - m) - ls;
    } else if (tid == 80) {
      *ctr = 0u;                           // arrival counter (poisoned 0xAA)
    }
  }
}

// ---------------- LDS bodies (validated rounds 4/5/7/9/11/12) -------------
__device__ __forceinline__ void up_lds(int v, int lab, int gi, int g8,
    const float* asp, const float* __restrict__ sm_bT,
    float* sBeta, float* sNum, bool wantNum) {
  int ch0 = 4*v + 1;
  float ub = 0.f;
  #pragma unroll
  for (int l = 0; l < 4; ++l) {
    const float4* bp = (const float4*)(sBeta + (ch0 + l)*GC + g8);
    float4 b0 = bp[0], b1 = bp[1];
    ub += asp[l]*b0.x + asp[4+l]*b0.y + asp[8+l]*b0.z + asp[12+l]*b0.w
        + asp[16+l]*b1.x + asp[20+l]*b1.y + asp[24+l]*b1.z + asp[28+l]*b1.w;
  }
  float tmp = sm_bT[lab*GC + gi] * ub;
  float s = grp8_sum(tmp);
  sBeta[v*GC + gi] = tmp / s;
  if (wantNum) sNum[v*GC + gi] = ub;
}

__device__ __forceinline__ double down_lds(int v, int lab, float e, int gi, int g8,
    const float* asp, const float* aal, const float* lsp,
    const float* __restrict__ log_bT, float* sBeta, const float* sNum) {
  float pe = e / sNum[v*GC + gi];
  int ch0 = 4*v + 1;
  float local = 0.f;
  #pragma unroll
  for (int l = 0; l < 4; ++l) {
    float4* bp = (float4*)(sBeta + (ch0 + l)*GC + g8);
    float4 b0 = bp[0], b1 = bp[1];
    float S = asp[l]*b0.x + asp[4+l]*b0.y + asp[8+l]*b0.z + asp[12+l]*b0.w
            + asp[16+l]*b1.x + asp[20+l]*b1.y + asp[24+l]*b1.z + asp[28+l]*b1.w;
    float A = aal[l]*b0.x + aal[4+l]*b0.y + aal[8+l]*b0.z + aal[12+l]*b0.w
            + aal[16+l]*b1.x + aal[20+l]*b1.y + aal[24+l]*b1.z + aal[28+l]*b1.w;
    float ce = pe * S;
    sBeta[(ch0 + l)*GC + gi] = ce;          // beta slot -> eps
    local += pe*A + ce*lsp[l];
  }
  return (double)local + (double)(e * log_bT[lab*GC + gi]);
}

// ---------------- up: 256 subtrees in LDS; store full subtree state -------
__global__ __launch_bounds__(512, 1) void up_kernel(
    const float* __restrict__ a_sp, const float* __restrict__ sm_bT,
    const float* __restrict__ sm_piT, const int* __restrict__ t,
    float* __restrict__ betaS, float* __restrict__ numS) {
  __shared__ float sBeta[85*GC];            // 42.5 KB
  __shared__ float sNum[21*GC];             // 10.5 KB
  const int blk = blockIdx.x, tid = threadIdx.x;
  const int gi = tid & 127, g = gi >> 3, i = gi & 7, g8 = g*8, w = tid >> 7; // w 0..3
  float asp[32];
  {
    const float4* pa = (const float4*)(a_sp + g*256 + i*32);
    #pragma unroll
    for (int q = 0; q < 8; ++q) {
      float4 v = pa[q];
      asp[q*4+0]=v.x; asp[q*4+1]=v.y; asp[q*4+2]=v.z; asp[q*4+3]=v.w;
    }
  }
  const int base_leaf = SL + blk*64;
  #pragma unroll
  for (int it = 0; it < 16; ++it) {         // leaves: locals 21..84
    int k = it*4 + w;
    float bt = sm_piT[(k & 3)*GC + gi] * sm_bT[t[(base_leaf + k)*7]*GC + gi];
    float s = grp8_sum(bt);
    sBeta[(21 + k)*GC + gi] = bt / s;
  }
  __syncthreads();
  #pragma unroll
  for (int it = 0; it < 4; ++it) {          // level 6: locals 5..20
    int k = it*4 + w;
    up_lds(5 + k, t[(1365 + blk*16 + k)*7], gi, g8, asp, sm_bT, sBeta, sNum, true);
  }
  __syncthreads();
  up_lds(1 + w, t[(341 + blk*4 + w)*7], gi, g8, asp, sm_bT, sBeta, sNum, true); // lvl5
  __syncthreads();
  if (tid < 128)                            // subtree root: local 0
    up_lds(0, t[(85 + blk)*7], gi, g8, asp, sm_bT, sBeta, sNum, true);
  __syncthreads();
  // bulk store: full subtree beta (85 rows) + num (21 rows) -> global
  {
    const float4* srcB = (const float4*)sBeta;
    float4* dstB = (float4*)(betaS + (size_t)blk*85*GC);
    for (int n = tid; n < 85*GC/4; n += 512) dstB[n] = srcB[n];
    const float4* srcN = (const float4*)sNum;
    float4* dstN = (float4*)(numS + (size_t)blk*21*GC);
    for (int n = tid; n < 21*GC/4; n += 512) dstN[n] = srcN[n];
  }
}

// ---------------- downall: redundant top + own path + subtree down --------
__global__ __launch_bounds__(512, 1) void downall_kernel(
    const float* __restrict__ a_sp, const float* __restrict__ log_a,
    const float* __restrict__ log_sp, const float* __restrict__ sm_bT,
    const float* __restrict__ log_bT, const float* __restrict__ sm_piT,
    const float* __restrict__ log_piT, const int* __restrict__ t,
    const float* __restrict__ betaS, const float* __restrict__ numS,
    unsigned* __restrict__ ctr, double* __restrict__ partial,
    float* __restrict__ out) {
  __shared__ float  sBeta[85*GC];           // top first, then subtree (42.5 KB)
  __shared__ float  sNum[21*GC];            // ids 0..20 ONLY (10.5 KB)
  __shared__ float  sEps[GC];               // own subtree-root eps
  __shared__ double sd[64];
  __shared__ double sfin[256];
  __shared__ unsigned lastFlag;
  const int blk = blockIdx.x, tid = threadIdx.x;
  const int gi = tid & 127, g = gi >> 3, i = gi & 7, g8 = g*8, w = tid >> 7; // w 0..3
  float asp[32], aal[32], lsp[4];
  {
    const float4* pa = (const float4*)(a_sp  + g*256 + i*32);
    const float4* pl = (const float4*)(log_a + g*256 + i*32);
    #pragma unroll
    for (int k = 0; k < 8; ++k) {
      float4 va = pa[k], vl = pl[k];
      asp[k*4+0]=va.x; asp[k*4+1]=va.y; asp[k*4+2]=va.z; asp[k*4+3]=va.w;
      aal[k*4+0]=va.x*vl.x; aal[k*4+1]=va.y*vl.y; aal[k*4+2]=va.z*vl.z; aal[k*4+3]=va.w*vl.w;
    }
    #pragma unroll
    for (int l = 0; l < 4; ++l) lsp[l] = log_sp[g*4 + l];
  }

  // ===== phase A: top-up in LDS (nodes 0..84; node id == LDS slot) =====
  // subtree-root beta of global node 85+q lives at betaS[q*85*GC] (row 0).
  #pragma unroll
  for (int it = 0; it < 16; ++it) {         // level 3: 64 nodes, global children
    int k = it*4 + w, u = 21 + k;           // children = roots q = 4k+0..3
    float ub = 0.f;
    #pragma unroll
    for (int l = 0; l < 4; ++l) {
      const float4* bp = (const float4*)(betaS + (size_t)(4*k + l)*85*GC + g8);
      float4 b0 = bp[0], b1 = bp[1];
      ub += asp[l]*b0.x + asp[4+l]*b0.y + asp[8+l]*b0.z + asp[12+l]*b0.w
          + asp[16+l]*b1.x + asp[20+l]*b1.y + asp[24+l]*b1.z + asp[28+l]*b1.w;
    }
    float tmp = sm_bT[t[u*7]*GC + gi] * ub;
    float s = grp8_sum(tmp);
    sBeta[u*GC + gi] = tmp / s;             // numbeta for 21..84 NOT stored
  }
  __syncthreads();
  #pragma unroll
  for (int it = 0; it < 4; ++it) {          // level 2: nodes 5..20
    int u = 5 + it*4 + w;
    up_lds(u, t[u*7], gi, g8, asp, sm_bT, sBeta, sNum, true);
  }
  __syncthreads();
  up_lds(1 + w, t[(1 + w)*7], gi, g8, asp, sm_bT, sBeta, sNum, true);   // lvl1
  __syncthreads();
  if (tid < 128)                            // root
    up_lds(0, t[0], gi, g8, asp, sm_bT, sBeta, sNum, true);
  __syncthreads();

  // ===== phase B: own subtree-root eps via the 4-step root path; =====
  // ===== blk%4==0 also contributes its level-3 ancestor a3's terms =====
  double acc = 0.0;
  if (tid < 128) {
    int a1 = 1 + (blk >> 6), a2 = 5 + (blk >> 4), a3 = 21 + (blk >> 2);
    float e = sBeta[gi];                    // eps(root) = beta(root)
    int anc[3] = {0, a1, a2};
    int chn[3] = {a1, a2, a3};
    #pragma unroll
    for (int s2 = 0; s2 < 3; ++s2) {        // anc ids 0..20: sNum valid
      float pe = e / sNum[anc[s2]*GC + gi];
      int l = (chn[s2] - 1) & 3;
      const float4* bp = (const float4*)(sBeta + chn[s2]*GC + g8);
      float4 b0 = bp[0], b1 = bp[1];
      float S = asp[l]*b0.x + asp[4+l]*b0.y + asp[8+l]*b0.z + asp[12+l]*b0.w
              + asp[16+l]*b1.x + asp[20+l]*b1.y + asp[24+l]*b1.z + asp[28+l]*b1.w;
      e = pe * S;
    }
    // final step a3 -> own root (85+blk): num(a3)/Sv/Av from betaS roots
    // children of a3 are roots q = (blk & ~3) + l
    float Sv[4], Av[4], num3 = 0.f;
    int qbase = blk & ~3;
    #pragma unroll
    for (int l = 0; l < 4; ++l) {
      const float4* bp = (const float4*)(betaS + (size_t)(qbase + l)*85*GC + g8);
      float4 b0 = bp[0], b1 = bp[1];
      Sv[l] = asp[l]*b0.x + asp[4+l]*b0.y + asp[8+l]*b0.z + asp[12+l]*b0.w
            + asp[16+l]*b1.x + asp[20+l]*b1.y + asp[24+l]*b1.z + asp[28+l]*b1.w;
      num3 += Sv[l];
      Av[l] = aal[l]*b0.x + aal[4+l]*b0.y + aal[8+l]*b0.z + aal[12+l]*b0.w
            + aal[16+l]*b1.x + aal[20+l]*b1.y + aal[24+l]*b1.z + aal[28+l]*b1.w;
    }
    float e3 = e;
    float pe3 = e3 / num3;
    sEps[gi] = pe3 * Sv[blk & 3];
    if ((blk & 3) == 0) {                   // distributed level-3 contribution
      float local = 0.f;
      #pragma unroll
      for (int l = 0; l < 4; ++l) local += pe3*Av[l] + (pe3*Sv[l])*lsp[l];
      acc += (double)local + (double)(e3 * log_bT[t[a3*7]*GC + gi]);
    }
  }
  __syncthreads();

  // ===== phase C: block 0 only — top-down for nodes 0..20 =====
  if (blk == 0) {
    if (tid < 128)
      acc += down_lds(0, t[0], sBeta[gi], gi, g8, asp, aal, lsp, log_bT, sBeta, sNum);
    __syncthreads();
    {
      int v = 1 + w;
      acc += down_lds(v, t[v*7], sBeta[v*GC + gi], gi, g8, asp, aal, lsp, log_bT, sBeta, sNum);
    }
    __syncthreads();
    #pragma unroll
    for (int it = 0; it < 4; ++it) {
      int v = 5 + it*4 + w;
      acc += down_lds(v, t[v*7], sBeta[v*GC + gi], gi, g8, asp, aal, lsp, log_bT, sBeta, sNum);
    }
    __syncthreads();                        // protect sBeta reuse below
  }

  // ===== phase D': bulk reload of subtree state (replaces up redo) =====
  {
    const float4* srcB = (const float4*)(betaS + (size_t)blk*85*GC);
    float4* dstB = (float4*)sBeta;
    for (int n = tid; n < 85*GC/4; n += 512) dstB[n] = srcB[n];
    const float4* srcN = (const float4*)(numS + (size_t)blk*21*GC);
    float4* dstN = (float4*)sNum;
    for (int n = tid; n < 21*GC/4; n += 512) dstN[n] = srcN[n];
  }
  __syncthreads();

  // ===== phase E: subtree down + fused per-block reduction =====
  const int base_leaf = SL + blk*64;
  if (tid < 128)
    acc += down_lds(0, t[(85 + blk)*7], sEps[gi], gi, g8, asp, aal, lsp,
                    log_bT, sBeta, sNum);
  __syncthreads();
  {                                         // level 5 (locals 1..4)
    int v = 1 + w;
    acc += down_lds(v, t[(341 + blk*4 + w)*7], sBeta[v*GC + gi], gi, g8,
                    asp, aal, lsp, log_bT, sBeta, sNum);
  }
  __syncthreads();
  #pragma unroll
  for (int it = 0; it < 4; ++it) {          // level 6 (locals 5..20)
    int k = it*4 + w, v = 5 + k;
    acc += down_lds(v, t[(1365 + blk*16 + k)*7], sBeta[v*GC + gi], gi, g8,
                    asp, aal, lsp, log_bT, sBeta, sNum);
  }
  __syncthreads();
  #pragma unroll
  for (int it = 0; it < 16; ++it) {         // leaves: b_lh + pi_lh
    int k = it*4 + w;
    float e = sBeta[(21 + k)*GC + gi];
    acc += (double)(e * (log_bT[t[(base_leaf + k)*7]*GC + gi] +
                         log_piT[(k & 3)*GC + gi]));
  }

  // per-block reduction -> double partial (plain stores, no atomic burst)
  acc += __shfl_xor(acc, 1);
  acc += __shfl_xor(acc, 2);
  acc += __shfl_xor(acc, 4);
  if (i == 0) sd[tid >> 3] = acc;           // tid>>3 = w*16 + g (0..63)
  __syncthreads();
  if (tid < 16) partial[blk*16 + tid] = sd[tid] + sd[16 + tid] + sd[32 + tid] + sd[48 + tid];
  __syncthreads();

  // one ACQ_REL arrival per block; LAST block reduces 256x16 and writes out
  if (tid == 0) {
    unsigned old = __hip_atomic_fetch_add(ctr, 1u, __ATOMIC_ACQ_REL,
                                          __HIP_MEMORY_SCOPE_AGENT);
    lastFlag = (old == 255u);
  }
  __syncthreads();
  if (lastFlag) {
    if (tid < 256) {
      int gg = tid & 15, ch = tid >> 4;     // 16 chunks x 16 blocks
      const double* p = partial + (size_t)ch*256 + gg;
      double s = 0.0;
      #pragma unroll
      for (int q = 0; q < 16; ++q) s += p[q*16];
      sfin[tid] = s;
    }
    __syncthreads();
    if (tid < 16) {
      double tot = 0.0;
      #pragma unroll
      for (int ch = 0; ch < 16; ++ch) tot += sfin[ch*16 + tid];
      out[tid] = (float)tot;
    }
  }
}

extern "C" void kernel_launch(void* const* d_in, const int* in_sizes, int n_in,
                              void* d_out, int out_size, void* d_ws, size_t ws_size,
                              hipStream_t stream) {
  const int*   t  = (const int*)d_in[0];
  // d_in[1] = t_limits (tree shape is compile-time constant)
  const float* a  = (const float*)d_in[2];
  const float* b  = (const float*)d_in[3];
  const float* pi = (const float*)d_in[4];
  const float* sp = (const float*)d_in[5];
  float* out = (float*)d_out;

  char* w = (char*)d_ws;
  size_t off = 0;
  auto carve = [&](size_t bytes) -> void* {
    void* ptr = w + off;
    off += (bytes + 255) & ~(size_t)255;
    return ptr;
  };
  float*    a_sp    = (float*)carve((size_t)16*8*8*4*4);
  float*    log_a   = (float*)carve((size_t)16*8*8*4*4);
  float*    sm_bT   = (float*)carve((size_t)256*GC*4);
  float*    log_bT  = (float*)carve((size_t)256*GC*4);
  float*    sm_piT  = (float*)carve((size_t)4*GC*4);
  float*    log_piT = (float*)carve((size_t)4*GC*4);
  float*    log_sp  = (float*)carve((size_t)16*4*4);
  float*    betaS   = (float*)carve((size_t)256*85*GC*4); // per-subtree betas
  float*    numS    = (float*)carve((size_t)256*21*GC*4); // per-subtree nums
  double*   partial = (double*)carve((size_t)256*16*8);   // per-block partials
  unsigned* ctr     = (unsigned*)carve((size_t)4);        // arrival counter

  setup_kernel<<<130, 256, 0, stream>>>(a, b, pi, sp, a_sp, log_a, sm_bT, log_bT,
                                        sm_piT, log_piT, log_sp, ctr);
  up_kernel<<<256, 512, 0, stream>>>(a_sp, sm_bT, sm_piT, t, betaS, numS);
  downall_kernel<<<256, 512, 0, stream>>>(a_sp, log_a, log_sp, sm_bT, log_bT,
                                          sm_piT, log_piT, t, betaS, numS,
                                          ctr, partial, out);
}

// Round 6
// 105.569 us; speedup vs baseline: 3.1308x; 1.0145x over previous
//
#include <hip/hip_runtime.h>

// Bottom-up HTMM on a complete 4-ary tree, depth 7 (t_size=21845).
// children(u)=4u+1..4u+4, pos(u)=(u-1)&3; only labels t[u*7] are data.
// prior cancels everywhere (only numbeta = prior*beta_il is used).
//
// R15 == R14 resubmitted verbatim (R14 bench failed with
// GPUAcquisitionTimeout — infra, not kernel; no counters were produced).
//
// R14: 3-kernel structure (kernel boundary = only cheap grid barrier on
// gfx950; R10/R11: grid.sync ~80us, hand spin ~55us). Changes vs R13:
//  - up_kernel additionally stores root betas COMPACT in betaG[256*GC]
//    (128 KB, L2-hot); downall phases A/B read betaG instead of strided
//    betaS rows (43.5 KB apart). Same arithmetic, same bits.
//  - downall register-stages the 53 KB subtree reload (8 float4/thread)
//    at kernel start; loads drain at phase A's first barrier -> latency
//    fully hidden under A's compute. LDS writes happen at old D' spot.
//  - phase C distributed: top node v's contribution on block v (eps via
//    ancestor walk, bit-identical ops); block 0 no longer a serial tail.
// Kept: partial[] + one ACQ_REL arrival per block, LAST block reduces;
// distributed level-3 contribution (blk%4==0); parallel setup (1 b-row
// per block). R9 lesson: 512-thread blocks (no VGPR-cap spill).

#define G 16
#define C 8
#define GC 128
#define TSIZE 21845
#define SL 5461

__device__ __forceinline__ float grp8_sum(float v) {
  v += __shfl_xor(v, 1);
  v += __shfl_xor(v, 2);
  v += __shfl_xor(v, 4);
  return v;
}

// single-column matvec: sum_j asp[j*4+l] * row[g8+j]
__device__ __forceinline__ float matv(const float* asp, const float* row, int l, int g8) {
  const float4* bp = (const float4*)(row + g8);
  float4 b0 = bp[0], b1 = bp[1];
  return asp[l]*b0.x + asp[4+l]*b0.y + asp[8+l]*b0.z + asp[12+l]*b0.w
       + asp[16+l]*b1.x + asp[20+l]*b1.y + asp[24+l]*b1.z + asp[28+l]*b1.w;
}

// ---------------- setup: softmaxes + logs (transposed tables) -------------
// grid 130 x 256: blocks 0..127 one b-row each; 128 = a/sp; 129 = pi/sp/ctr.
__global__ void setup_kernel(const float* __restrict__ ain, const float* __restrict__ bin,
                             const float* __restrict__ piin, const float* __restrict__ spin,
                             float* __restrict__ a_sp, float* __restrict__ log_a,
                             float* __restrict__ sm_bT, float* __restrict__ log_bT,
                             float* __restrict__ sm_piT, float* __restrict__ log_piT,
                             float* __restrict__ log_sp, unsigned* __restrict__ ctr) {
  int blk = blockIdx.x, tid = threadIdx.x;
  if (blk < 128) {
    // softmax over labels (M=256) for one row (g,c); write transposed [lab][row]
    __shared__ float red4[4];
    int row = blk;                       // g*8 + c
    float x = bin[row * 256 + tid];      // tid = lab
    float m = x;
    #pragma unroll
    for (int off2 = 32; off2; off2 >>= 1) m = fmaxf(m, __shfl_xor(m, off2));
    if ((tid & 63) == 0) red4[tid >> 6] = m;
    __syncthreads();
    m = fmaxf(fmaxf(red4[0], red4[1]), fmaxf(red4[2], red4[3]));
    __syncthreads();
    float e = expf(x - m);
    float ssum = e;
    #pragma unroll
    for (int off2 = 32; off2; off2 >>= 1) ssum += __shfl_xor(ssum, off2);
    if ((tid & 63) == 0) red4[tid >> 6] = ssum;
    __syncthreads();
    ssum = red4[0] + red4[1] + red4[2] + red4[3];
    sm_bT[tid * GC + row]  = e / ssum;
    log_bT[tid * GC + row] = (x - m) - logf(ssum);
  } else if (blk == 128) {
    // softmax of a over i (axis=1), times sm_sp -> a_sp; also log(sm_a)
    for (int col = tid; col < 512; col += 256) {
      int g = col >> 5, j = (col >> 2) & 7, l = col & 3;
      float x[8], m = -1e30f;
      #pragma unroll
      for (int i = 0; i < 8; ++i) { x[i] = ain[g*256 + i*32 + j*4 + l]; m = fmaxf(m, x[i]); }
      float ssum = 0.f;
      #pragma unroll
      for (int i = 0; i < 8; ++i) ssum += expf(x[i] - m);
      float ls = logf(ssum);
      float y0 = spin[g*4+0], y1 = spin[g*4+1], y2 = spin[g*4+2], y3 = spin[g*4+3];
      float ms = fmaxf(fmaxf(y0, y1), fmaxf(y2, y3));
      float d = expf(y0-ms) + expf(y1-ms) + expf(y2-ms) + expf(y3-ms);
      float spv = expf(spin[g*4+l] - ms) / d;
      #pragma unroll
      for (int i = 0; i < 8; ++i) {
        int o2 = g*256 + i*32 + j*4 + l;
        float smv = expf(x[i] - m) / ssum;
        a_sp[o2]  = smv * spv;
        log_a[o2] = (x[i] - m) - ls;
      }
    }
  } else {
    if (tid < 64) {
      // softmax of pi over c (axis=1) for each (g,l); transposed [l][g*8+c]
      int g = tid >> 2, l = tid & 3;
      float x[8], m = -1e30f;
      #pragma unroll
      for (int c = 0; c < 8; ++c) { x[c] = piin[g*32 + c*4 + l]; m = fmaxf(m, x[c]); }
      float ssum = 0.f;
      #pragma unroll
      for (int c = 0; c < 8; ++c) ssum += expf(x[c] - m);
      float ls = logf(ssum);
      #pragma unroll
      for (int c = 0; c < 8; ++c) {
        sm_piT[l*GC + g*8 + c]  = expf(x[c] - m) / ssum;
        log_piT[l*GC + g*8 + c] = (x[c] - m) - ls;
      }
    } else if (tid < 80) {
      // log softmax of sp over l
      int g = tid - 64;
      float y[4], m = -1e30f;
      #pragma unroll
      for (int l = 0; l < 4; ++l) { y[l] = spin[g*4 + l]; m = fmaxf(m, y[l]); }
      float ssum = 0.f;
      #pragma unroll
      for (int l = 0; l < 4; ++l) ssum += expf(y[l] - m);
      float ls = logf(ssum);
      #pragma unroll
      for (int l = 0; l < 4; ++l) log_sp[g*4 + l] = (y[l] - m) - ls;
    } else if (tid == 80) {
      *ctr = 0u;                           // arrival counter (poisoned 0xAA)
    }
  }
}

// ---------------- LDS bodies (validated rounds 4/5/7/9/11/12/13) ----------
__device__ __forceinline__ void up_lds(int v, int lab, int gi, int g8,
    const float* asp, const float* __restrict__ sm_bT,
    float* sBeta, float* sNum, bool wantNum) {
  int ch0 = 4*v + 1;
  float ub = 0.f;
  #pragma unroll
  for (int l = 0; l < 4; ++l) {
    const float4* bp = (const float4*)(sBeta + (ch0 + l)*GC + g8);
    float4 b0 = bp[0], b1 = bp[1];
    ub += asp[l]*b0.x + asp[4+l]*b0.y + asp[8+l]*b0.z + asp[12+l]*b0.w
        + asp[16+l]*b1.x + asp[20+l]*b1.y + asp[24+l]*b1.z + asp[28+l]*b1.w;
  }
  float tmp = sm_bT[lab*GC + gi] * ub;
  float s = grp8_sum(tmp);
  sBeta[v*GC + gi] = tmp / s;
  if (wantNum) sNum[v*GC + gi] = ub;
}

__device__ __forceinline__ double down_lds(int v, int lab, float e, int gi, int g8,
    const float* asp, const float* aal, const float* lsp,
    const float* __restrict__ log_bT, float* sBeta, const float* sNum) {
  float pe = e / sNum[v*GC + gi];
  int ch0 = 4*v + 1;
  float local = 0.f;
  #pragma unroll
  for (int l = 0; l < 4; ++l) {
    float4* bp = (float4*)(sBeta + (ch0 + l)*GC + g8);
    float4 b0 = bp[0], b1 = bp[1];
    float S = asp[l]*b0.x + asp[4+l]*b0.y + asp[8+l]*b0.z + asp[12+l]*b0.w
            + asp[16+l]*b1.x + asp[20+l]*b1.y + asp[24+l]*b1.z + asp[28+l]*b1.w;
    float A = aal[l]*b0.x + aal[4+l]*b0.y + aal[8+l]*b0.z + aal[12+l]*b0.w
            + aal[16+l]*b1.x + aal[20+l]*b1.y + aal[24+l]*b1.z + aal[28+l]*b1.w;
    float ce = pe * S;
    sBeta[(ch0 + l)*GC + gi] = ce;          // beta slot -> eps
    local += pe*A + ce*lsp[l];
  }
  return (double)local + (double)(e * log_bT[lab*GC + gi]);
}

// ---------------- up: 256 subtrees in LDS; store subtree state + roots ----
__global__ __launch_bounds__(512, 1) void up_kernel(
    const float* __restrict__ a_sp, const float* __restrict__ sm_bT,
    const float* __restrict__ sm_piT, const int* __restrict__ t,
    float* __restrict__ betaS, float* __restrict__ numS,
    float* __restrict__ betaG) {
  __shared__ float sBeta[85*GC];            // 42.5 KB
  __shared__ float sNum[21*GC];             // 10.5 KB
  const int blk = blockIdx.x, tid = threadIdx.x;
  const int gi = tid & 127, g = gi >> 3, i = gi & 7, g8 = g*8, w = tid >> 7; // w 0..3
  float asp[32];
  {
    const float4* pa = (const float4*)(a_sp + g*256 + i*32);
    #pragma unroll
    for (int q = 0; q < 8; ++q) {
      float4 v = pa[q];
      asp[q*4+0]=v.x; asp[q*4+1]=v.y; asp[q*4+2]=v.z; asp[q*4+3]=v.w;
    }
  }
  const int base_leaf = SL + blk*64;
  #pragma unroll
  for (int it = 0; it < 16; ++it) {         // leaves: locals 21..84
    int k = it*4 + w;
    float bt = sm_piT[(k & 3)*GC + gi] * sm_bT[t[(base_leaf + k)*7]*GC + gi];
    float s = grp8_sum(bt);
    sBeta[(21 + k)*GC + gi] = bt / s;
  }
  __syncthreads();
  #pragma unroll
  for (int it = 0; it < 4; ++it) {          // level 6: locals 5..20
    int k = it*4 + w;
    up_lds(5 + k, t[(1365 + blk*16 + k)*7], gi, g8, asp, sm_bT, sBeta, sNum, true);
  }
  __syncthreads();
  up_lds(1 + w, t[(341 + blk*4 + w)*7], gi, g8, asp, sm_bT, sBeta, sNum, true); // lvl5
  __syncthreads();
  if (tid < 128) {                          // subtree root: local 0
    up_lds(0, t[(85 + blk)*7], gi, g8, asp, sm_bT, sBeta, sNum, true);
    betaG[(size_t)blk*GC + gi] = sBeta[gi]; // compact root copy (128 KB hot)
  }
  __syncthreads();
  // bulk store: full subtree beta (85 rows) + num (21 rows) -> global
  {
    const float4* srcB = (const float4*)sBeta;
    float4* dstB = (float4*)(betaS + (size_t)blk*85*GC);
    for (int n = tid; n < 85*GC/4; n += 512) dstB[n] = srcB[n];
    const float4* srcN = (const float4*)sNum;
    float4* dstN = (float4*)(numS + (size_t)blk*21*GC);
    for (int n = tid; n < 21*GC/4; n += 512) dstN[n] = srcN[n];
  }
}

// ---------------- downall: redundant top + own path + subtree down --------
__global__ __launch_bounds__(512, 1) void downall_kernel(
    const float* __restrict__ a_sp, const float* __restrict__ log_a,
    const float* __restrict__ log_sp, const float* __restrict__ sm_bT,
    const float* __restrict__ log_bT, const float* __restrict__ sm_piT,
    const float* __restrict__ log_piT, const int* __restrict__ t,
    const float* __restrict__ betaS, const float* __restrict__ numS,
    const float* __restrict__ betaG, unsigned* __restrict__ ctr,
    double* __restrict__ partial, float* __restrict__ out) {
  __shared__ float  sBeta[85*GC];           // top first, then subtree (42.5 KB)
  __shared__ float  sNum[21*GC];            // ids 0..20 ONLY (10.5 KB)
  __shared__ float  sEps[GC];               // own subtree-root eps
  __shared__ double sd[64];
  __shared__ double sfin[256];
  __shared__ unsigned lastFlag;
  const int blk = blockIdx.x, tid = threadIdx.x;
  const int gi = tid & 127, g = gi >> 3, i = gi & 7, g8 = g*8, w = tid >> 7; // w 0..3
  float asp[32], aal[32], lsp[4];
  {
    const float4* pa = (const float4*)(a_sp  + g*256 + i*32);
    const float4* pl = (const float4*)(log_a + g*256 + i*32);
    #pragma unroll
    for (int k = 0; k < 8; ++k) {
      float4 va = pa[k], vl = pl[k];
      asp[k*4+0]=va.x; asp[k*4+1]=va.y; asp[k*4+2]=va.z; asp[k*4+3]=va.w;
      aal[k*4+0]=va.x*vl.x; aal[k*4+1]=va.y*vl.y; aal[k*4+2]=va.z*vl.z; aal[k*4+3]=va.w*vl.w;
    }
    #pragma unroll
    for (int l = 0; l < 4; ++l) lsp[l] = log_sp[g*4 + l];
  }

  // ===== register-stage the subtree reload (drains at A's 1st barrier) ====
  float4 rB0, rB1, rB2, rB3, rB4, rB5, rN0, rN1;
  {
    const float4* srcB = (const float4*)(betaS + (size_t)blk*85*GC);
    rB0 = srcB[tid];        rB1 = srcB[tid + 512];
    rB2 = srcB[tid + 1024]; rB3 = srcB[tid + 1536];
    rB4 = srcB[tid + 2048];
    if (tid < 160) rB5 = srcB[tid + 2560];          // 85*128/4 = 2720
    const float4* srcN = (const float4*)(numS + (size_t)blk*21*GC);
    rN0 = srcN[tid];
    if (tid < 160) rN1 = srcN[tid + 512];           // 21*128/4 = 672
  }

  // ===== phase A: top-up in LDS (nodes 0..84) from compact betaG =========
  #pragma unroll
  for (int it = 0; it < 16; ++it) {         // level 3: 64 nodes, global children
    int k = it*4 + w, u = 21 + k;           // children = roots q = 4k+0..3
    float ub = 0.f;
    #pragma unroll
    for (int l = 0; l < 4; ++l)
      ub += matv(asp, betaG + (size_t)(4*k + l)*GC, l, g8);
    float tmp = sm_bT[t[u*7]*GC + gi] * ub;
    float s = grp8_sum(tmp);
    sBeta[u*GC + gi] = tmp / s;             // numbeta for 21..84 NOT stored
  }
  __syncthreads();
  #pragma unroll
  for (int it = 0; it < 4; ++it) {          // level 2: nodes 5..20
    int u = 5 + it*4 + w;
    up_lds(u, t[u*7], gi, g8, asp, sm_bT, sBeta, sNum, true);
  }
  __syncthreads();
  up_lds(1 + w, t[(1 + w)*7], gi, g8, asp, sm_bT, sBeta, sNum, true);   // lvl1
  __syncthreads();
  if (tid < 128)                            // root
    up_lds(0, t[0], gi, g8, asp, sm_bT, sBeta, sNum, true);
  __syncthreads();

  // ===== phase B: own subtree-root eps via the 4-step root path; =====
  // ===== blk%4==0 also contributes its level-3 ancestor a3's terms =====
  double acc = 0.0;
  if (tid < 128) {
    int a1 = 1 + (blk >> 6), a2 = 5 + (blk >> 4), a3 = 21 + (blk >> 2);
    float e = sBeta[gi];                    // eps(root) = beta(root)
    int anc[3] = {0, a1, a2};
    int chn[3] = {a1, a2, a3};
    #pragma unroll
    for (int s2 = 0; s2 < 3; ++s2) {        // anc ids 0..20: sNum valid
      float pe = e / sNum[anc[s2]*GC + gi];
      int l = (chn[s2] - 1) & 3;
      e = pe * matv(asp, sBeta + chn[s2]*GC, l, g8);
    }
    // final step a3 -> own root (85+blk): num(a3)/Sv/Av from compact betaG
    float Sv[4], Av[4], num3 = 0.f;
    int qbase = blk & ~3;                   // children of a3 = roots qbase+l
    #pragma unroll
    for (int l = 0; l < 4; ++l) {
      const float4* bp = (const float4*)(betaG + (size_t)(qbase + l)*GC + g8);
      float4 b0 = bp[0], b1 = bp[1];
      Sv[l] = asp[l]*b0.x + asp[4+l]*b0.y + asp[8+l]*b0.z + asp[12+l]*b0.w
            + asp[16+l]*b1.x + asp[20+l]*b1.y + asp[24+l]*b1.z + asp[28+l]*b1.w;
      num3 += Sv[l];
      Av[l] = aal[l]*b0.x + aal[4+l]*b0.y + aal[8+l]*b0.z + aal[12+l]*b0.w
            + aal[16+l]*b1.x + aal[20+l]*b1.y + aal[24+l]*b1.z + aal[28+l]*b1.w;
    }
    float e3 = e;
    float pe3 = e3 / num3;
    sEps[gi] = pe3 * Sv[blk & 3];
    if ((blk & 3) == 0) {                   // distributed level-3 contribution
      float local = 0.f;
      #pragma unroll
      for (int l = 0; l < 4; ++l) local += pe3*Av[l] + (pe3*Sv[l])*lsp[l];
      acc += (double)local + (double)(e3 * log_bT[t[a3*7]*GC + gi]);
    }
  }

  // ===== phase C: distributed — top node v's contribution on block v ======
  // eps(v) via the ancestor walk: bit-identical ops to the old chained
  // down_lds version (same pe = e/num, same single-l matvec expression).
  if (blk < 21 && tid < 128) {
    int v = blk;
    float e;
    if (v == 0) {
      e = sBeta[gi];
    } else {
      int p = (v - 1) >> 2;                 // 0 for 1..4; 1..4 for 5..20
      float pe = sBeta[gi] / sNum[gi];      // pe(root)
      if (p == 0) {
        e = pe * matv(asp, sBeta + v*GC, (v - 1) & 3, g8);
      } else {
        float ep = pe * matv(asp, sBeta + p*GC, (p - 1) & 3, g8);
        float pe2 = ep / sNum[p*GC + gi];
        e = pe2 * matv(asp, sBeta + v*GC, (v - 1) & 3, g8);
      }
    }
    acc += down_lds(v, t[v*7], e, gi, g8, asp, aal, lsp, log_bT, sBeta, sNum);
  }
  __syncthreads();                          // top reads done; LDS reusable

  // ===== phase D': write register-staged subtree state into LDS ===========
  {
    float4* dstB = (float4*)sBeta;
    dstB[tid] = rB0;        dstB[tid + 512]  = rB1;
    dstB[tid + 1024] = rB2; dstB[tid + 1536] = rB3;
    dstB[tid + 2048] = rB4;
    if (tid < 160) dstB[tid + 2560] = rB5;
    float4* dstN = (float4*)sNum;
    dstN[tid] = rN0;
    if (tid < 160) dstN[tid + 512] = rN1;
  }
  __syncthreads();

  // ===== phase E: subtree down + fused per-block reduction =====
  const int base_leaf = SL + blk*64;
  if (tid < 128)
    acc += down_lds(0, t[(85 + blk)*7], sEps[gi], gi, g8, asp, aal, lsp,
                    log_bT, sBeta, sNum);
  __syncthreads();
  {                                         // level 5 (locals 1..4)
    int v = 1 + w;
    acc += down_lds(v, t[(341 + blk*4 + w)*7], sBeta[v*GC + gi], gi, g8,
                    asp, aal, lsp, log_bT, sBeta, sNum);
  }
  __syncthreads();
  #pragma unroll
  for (int it = 0; it < 4; ++it) {          // level 6 (locals 5..20)
    int k = it*4 + w, v = 5 + k;
    acc += down_lds(v, t[(1365 + blk*16 + k)*7], sBeta[v*GC + gi], gi, g8,
                    asp, aal, lsp, log_bT, sBeta, sNum);
  }
  __syncthreads();
  #pragma unroll
  for (int it = 0; it < 16; ++it) {         // leaves: b_lh + pi_lh
    int k = it*4 + w;
    float e = sBeta[(21 + k)*GC + gi];
    acc += (double)(e * (log_bT[t[(base_leaf + k)*7]*GC + gi] +
                         log_piT[(k & 3)*GC + gi]));
  }

  // per-block reduction -> double partial (plain stores, no atomic burst)
  acc += __shfl_xor(acc, 1);
  acc += __shfl_xor(acc, 2);
  acc += __shfl_xor(acc, 4);
  if (i == 0) sd[tid >> 3] = acc;           // tid>>3 = w*16 + g (0..63)
  __syncthreads();
  if (tid < 16) partial[blk*16 + tid] = sd[tid] + sd[16 + tid] + sd[32 + tid] + sd[48 + tid];
  __syncthreads();

  // one ACQ_REL arrival per block; LAST block reduces 256x16 and writes out
  if (tid == 0) {
    unsigned old = __hip_atomic_fetch_add(ctr, 1u, __ATOMIC_ACQ_REL,
                                          __HIP_MEMORY_SCOPE_AGENT);
    lastFlag = (old == 255u);
  }
  __syncthreads();
  if (lastFlag) {
    if (tid < 256) {
      int gg = tid & 15, ch = tid >> 4;     // 16 chunks x 16 blocks
      const double* p = partial + (size_t)ch*256 + gg;
      double s = 0.0;
      #pragma unroll
      for (int q = 0; q < 16; ++q) s += p[q*16];
      sfin[tid] = s;
    }
    __syncthreads();
    if (tid < 16) {
      double tot = 0.0;
      #pragma unroll
      for (int ch = 0; ch < 16; ++ch) tot += sfin[ch*16 + tid];
      out[tid] = (float)tot;
    }
  }
}

extern "C" void kernel_launch(void* const* d_in, const int* in_sizes, int n_in,
                              void* d_out, int out_size, void* d_ws, size_t ws_size,
                              hipStream_t stream) {
  const int*   t  = (const int*)d_in[0];
  // d_in[1] = t_limits (tree shape is compile-time constant)
  const float* a  = (const float*)d_in[2];
  const float* b  = (const float*)d_in[3];
  const float* pi = (const float*)d_in[4];
  const float* sp = (const float*)d_in[5];
  float* out = (float*)d_out;

  char* w = (char*)d_ws;
  size_t off = 0;
  auto carve = [&](size_t bytes) -> void* {
    void* ptr = w + off;
    off += (bytes + 255) & ~(size_t)255;
    return ptr;
  };
  float*    a_sp    = (float*)carve((size_t)16*8*8*4*4);
  float*    log_a   = (float*)carve((size_t)16*8*8*4*4);
  float*    sm_bT   = (float*)carve((size_t)256*GC*4);
  float*    log_bT  = (float*)carve((size_t)256*GC*4);
  float*    sm_piT  = (float*)carve((size_t)4*GC*4);
  float*    log_piT = (float*)carve((size_t)4*GC*4);
  float*    log_sp  = (float*)carve((size_t)16*4*4);
  float*    betaS   = (float*)carve((size_t)256*85*GC*4); // per-subtree betas
  float*    numS    = (float*)carve((size_t)256*21*GC*4); // per-subtree nums
  float*    betaG   = (float*)carve((size_t)256*GC*4);    // compact root betas
  double*   partial = (double*)carve((size_t)256*16*8);   // per-block partials
  unsigned* ctr     = (unsigned*)carve((size_t)4);        // arrival counter

  setup_kernel<<<130, 256, 0, stream>>>(a, b, pi, sp, a_sp, log_a, sm_bT, log_bT,
                                        sm_piT, log_piT, log_sp, ctr);
  up_kernel<<<256, 512, 0, stream>>>(a_sp, sm_bT, sm_piT, t, betaS, numS, betaG);
  downall_kernel<<<256, 512, 0, stream>>>(a_sp, log_a, log_sp, sm_bT, log_bT,
                                          sm_piT, log_piT, t, betaS, numS,
                                          betaG, ctr, partial, out);
}